// Round 9
// baseline (173.259 us; speedup 1.0000x reference)
//
#include <hip/hip_runtime.h>
#include <hip/hip_bf16.h>
#include <math.h>

#define NTOK 2048
#define CDIM 256
#define HHEADS 8
#define DHEAD 32
#define NEDGE 32768
#define NTILE 16          // edge-CSR buckets per row (dst >> 7), 128-wide
#define SPLITS 8
#define TPS 2             // tiles per split (KBLK=128)
#define EXTD 64           // ext head dim (32 qk + 8 bias + 24 zero)
#define LE 72             // ext LDS row stride (shorts)

typedef __attribute__((ext_vector_type(8))) short short8;
typedef __attribute__((ext_vector_type(4))) short short4v;
typedef __attribute__((ext_vector_type(4))) float f32x4;

static __device__ inline short f2bf(float f) {
    __hip_bfloat16 h = __float2bfloat16(f);
    return *reinterpret_cast<short*>(&h);
}
static __device__ inline float bf2f(short s) {
    unsigned int u = ((unsigned int)(unsigned short)s) << 16;
    return *reinterpret_cast<float*>(&u);
}

// ---------------- LayerNorm: 4 rows/block, one wave per row, shuffle-only ------
__global__ __launch_bounds__(256) void ln4_kernel(const float* __restrict__ X,
    const float* __restrict__ g, const float* __restrict__ b, short* __restrict__ out)
{
    int t = threadIdx.x;
    int wv = t >> 6, lane = t & 63;
    int row = blockIdx.x * 4 + wv;

    float4 x = *(const float4*)&X[(size_t)row * CDIM + lane * 4];
    float s = x.x + x.y + x.z + x.w;
    #pragma unroll
    for (int off = 1; off < 64; off <<= 1) s += __shfl_xor(s, off);
    float mu = s * (1.0f / CDIM);
    float4 d = { x.x - mu, x.y - mu, x.z - mu, x.w - mu };
    float s2 = d.x * d.x + d.y * d.y + d.z * d.z + d.w * d.w;
    #pragma unroll
    for (int off = 1; off < 64; off <<= 1) s2 += __shfl_xor(s2, off);
    float rsig = rsqrtf(s2 * (1.0f / CDIM) + 1e-5f);
    float4 gg = *(const float4*)&g[lane * 4];
    float4 bb = *(const float4*)&b[lane * 4];
    short o4[4];
    o4[0] = f2bf(d.x * rsig * gg.x + bb.x);
    o4[1] = f2bf(d.y * rsig * gg.y + bb.y);
    o4[2] = f2bf(d.z * rsig * gg.z + bb.z);
    o4[3] = f2bf(d.w * rsig * gg.w + bb.w);
    *(short4v*)&out[(size_t)row * CDIM + lane * 4] = *(short4v*)o4;
}

// ---------------- Transpose + bf16 convert: in[K][N] -> out[N][K] --------------
template<int SRCF>
static __device__ inline void transpose_tile(const void* __restrict__ in_,
    short* __restrict__ out, int K, int N, int k0, int n0, int t)
{
    __shared__ float tile[64][65];
    int r0 = t >> 4, c0 = (t & 15) * 4;
    #pragma unroll
    for (int i = 0; i < 4; i++) {
        int r = r0 + i * 16;
        const float* in = (const float*)in_;
        float4 v = *(const float4*)(in + (size_t)(k0 + r) * N + n0 + c0);
        tile[r][c0 + 0] = v.x; tile[r][c0 + 1] = v.y;
        tile[r][c0 + 2] = v.z; tile[r][c0 + 3] = v.w;
    }
    __syncthreads();
    #pragma unroll
    for (int i = 0; i < 4; i++) {
        int nr = r0 + i * 16;
        short o4[4];
        #pragma unroll
        for (int j = 0; j < 4; j++) o4[j] = f2bf(tile[c0 + j][nr]);
        *(short4v*)(out + (size_t)(n0 + nr) * K + k0 + c0) = *(short4v*)o4;
    }
}

// all 6 weight transposes in one launch (192 blocks)
__global__ __launch_bounds__(256) void transpose_all_kernel(
    const float* __restrict__ Wq, const float* __restrict__ Wk,
    const float* __restrict__ Wv, const float* __restrict__ Wo,
    const float* __restrict__ W1, const float* __restrict__ W2,
    short* __restrict__ wt_qkv, short* __restrict__ wot,
    short* __restrict__ w1t, short* __restrict__ w2t)
{
    int b = blockIdx.x;
    const float* src; short* dst; int K, N, bx, by;
    if (b < 64) {
        int m = b >> 4, r = b & 15;
        src = (m == 0) ? Wq : (m == 1) ? Wk : (m == 2) ? Wv : Wo;
        dst = (m == 0) ? wt_qkv : (m == 1) ? wt_qkv + 256 * 256
            : (m == 2) ? wt_qkv + 512 * 256 : wot;
        K = 256; N = 256; bx = r & 3; by = r >> 2;
    } else if (b < 128) {
        int r = b - 64; src = W1; dst = w1t; K = 256; N = 1024; bx = r & 15; by = r >> 4;
    } else {
        int r = b - 128; src = W2; dst = w2t; K = 1024; N = 256; bx = r & 3; by = r >> 2;
    }
    transpose_tile<0>(src, dst, K, N, by * 64, bx * 64, threadIdx.x);
}

// ---------------- Q/K ext dims (typepair folded into MFMA) --------------------
// qh/kh layout [h][2048][64]: dims 0..31 = q/k (QKV GEMM); 32..39: qh =
// typepair_bias[ttq][j][h], kh = onehot(j == ttk); 40..63 zero.
__global__ __launch_bounds__(256) void ext_build_kernel(
    const int* __restrict__ token_type, const float* __restrict__ typepair_bias,
    short* __restrict__ qh, short* __restrict__ kh)
{
    int idx = blockIdx.x * 256 + threadIdx.x;   // (row, h)
    int row = idx >> 3, h = idx & 7;
    int tt = token_type[row];
    short qe[32], ke[32];
    #pragma unroll
    for (int j = 0; j < 32; j++) {
        if (j < 8) {
            qe[j] = f2bf(typepair_bias[(tt * 8 + j) * 8 + h]);
            ke[j] = (j == tt) ? (short)0x3F80 : (short)0;   // bf16 1.0
        } else { qe[j] = 0; ke[j] = 0; }
    }
    size_t base = ((size_t)h * NTOK + row) * EXTD + 32;
    #pragma unroll
    for (int k = 0; k < 4; k++) {
        *(short8*)&qh[base + k * 8] = *(short8*)&qe[k * 8];
        *(short8*)&kh[base + k * 8] = *(short8*)&ke[k * 8];
    }
}

// ---------------- bf16 MFMA GEMM, 64x64 tile, BK=32, 256 thr -------------------
template<int EPI>
__global__ __launch_bounds__(256) void gemm_bf16_kernel(
    const short* __restrict__ A, const short* __restrict__ Bt,
    const float* __restrict__ bias, const float* __restrict__ resid,
    void* __restrict__ out_, int M, int N, int K)
{
    __shared__ short A_lds[64 * 40];
    __shared__ short B_lds[64 * 40];

    const int t = threadIdx.x;
    const int w = t >> 6, lane = t & 63, c = lane & 15, g = lane >> 4;
    const int row0 = blockIdx.y * 64, col0 = blockIdx.x * 64;
    const int arow = t >> 2, ak = (t & 3) * 8;

    f32x4 acc[4] = {};

    for (int k0 = 0; k0 < K; k0 += 32) {
        *(short8*)&A_lds[arow * 40 + ak] = *(const short8*)&A[(size_t)(row0 + arow) * K + k0 + ak];
        *(short8*)&B_lds[arow * 40 + ak] = *(const short8*)&Bt[(size_t)(col0 + arow) * K + k0 + ak];
        __syncthreads();
        short8 af = *(const short8*)&A_lds[(w * 16 + c) * 40 + g * 8];
        #pragma unroll
        for (int nf = 0; nf < 4; nf++) {
            short8 bf = *(const short8*)&B_lds[(nf * 16 + c) * 40 + g * 8];
            acc[nf] = __builtin_amdgcn_mfma_f32_16x16x32_bf16(af, bf, acc[nf], 0, 0, 0);
        }
        __syncthreads();
    }

    #pragma unroll
    for (int nf = 0; nf < 4; nf++) {
        #pragma unroll
        for (int reg = 0; reg < 4; reg++) {
            int row = row0 + w * 16 + g * 4 + reg;
            int col = col0 + nf * 16 + c;
            float v = acc[nf][reg] + bias[col];
            if (EPI == 2) {
                ((float*)out_)[(size_t)row * N + col] = v + resid[(size_t)row * N + col];
            } else {
                v = 0.5f * v * (1.0f + erff(v * 0.70710678118654752f));
                ((short*)out_)[(size_t)row * N + col] = f2bf(v);
            }
        }
    }
}

// Fused QKV GEMM: q -> qh[h][row][0..31] (scaled), k -> kh, v -> vt[256][2048]
__global__ __launch_bounds__(256) void gemm_qkv_kernel(
    const short* __restrict__ A, const short* __restrict__ Bt,
    const float* __restrict__ bq, const float* __restrict__ bk, const float* __restrict__ bv,
    short* __restrict__ qh, short* __restrict__ kh, short* __restrict__ vt)
{
    const int K = CDIM;
    __shared__ short A_lds[64 * 40];
    __shared__ short B_lds[64 * 40];

    const int t = threadIdx.x;
    const int w = t >> 6, lane = t & 63, c = lane & 15, g = lane >> 4;
    const int row0 = blockIdx.y * 64, col0 = blockIdx.x * 64;
    const int arow = t >> 2, ak = (t & 3) * 8;

    f32x4 acc[4] = {};

    for (int k0 = 0; k0 < K; k0 += 32) {
        *(short8*)&A_lds[arow * 40 + ak] = *(const short8*)&A[(size_t)(row0 + arow) * K + k0 + ak];
        *(short8*)&B_lds[arow * 40 + ak] = *(const short8*)&Bt[(size_t)(col0 + arow) * K + k0 + ak];
        __syncthreads();
        short8 af = *(const short8*)&A_lds[(w * 16 + c) * 40 + g * 8];
        #pragma unroll
        for (int nf = 0; nf < 4; nf++) {
            short8 bf = *(const short8*)&B_lds[(nf * 16 + c) * 40 + g * 8];
            acc[nf] = __builtin_amdgcn_mfma_f32_16x16x32_bf16(af, bf, acc[nf], 0, 0, 0);
        }
        __syncthreads();
    }

    const int region = col0 >> 8;           // 0=q, 1=k, 2=v
    const int colr0 = col0 & 255;
    const float* bias = (region == 0) ? bq : (region == 1) ? bk : bv;
    #pragma unroll
    for (int nf = 0; nf < 4; nf++) {
        #pragma unroll
        for (int reg = 0; reg < 4; reg++) {
            int row = row0 + w * 16 + g * 4 + reg;
            int col = colr0 + nf * 16 + c;
            float v = acc[nf][reg] + bias[col];
            if (region == 0) v *= 0.17677669529663687f;   // 1/sqrt(32)
            short bb = f2bf(v);
            size_t hidx = ((size_t)(col >> 5) * NTOK + row) * EXTD + (col & 31);
            if (region == 0)      qh[hidx] = bb;
            else if (region == 1) kh[hidx] = bb;
            else                  vt[(size_t)col * NTOK + row] = bb;   // V^T direct
        }
    }
}

// ---------------- Edge CSR build, bucketed by (src, dst>>7) --------------------
__global__ void edge_hist2_kernel(const int* __restrict__ src, const int* __restrict__ dst,
    int* __restrict__ cnt, int E)
{
    int e = blockIdx.x * blockDim.x + threadIdx.x;
    if (e < E) atomicAdd(&cnt[src[e] * NTILE + (dst[e] >> 7)], 1);
}

__global__ __launch_bounds__(256) void edge_scan2_kernel(const int* __restrict__ cnt,
    int* __restrict__ row_ptr, int* __restrict__ wcur)
{
    __shared__ int sums[256];
    int t = threadIdx.x;
    int base = t * 128;
    int s = 0;
    for (int i = 0; i < 128; i++) s += cnt[base + i];
    sums[t] = s;
    __syncthreads();
    for (int off = 1; off < 256; off <<= 1) {
        int v = (t >= off) ? sums[t - off] : 0;
        __syncthreads();
        sums[t] += v;
        __syncthreads();
    }
    int run = (t == 0) ? 0 : sums[t - 1];
    for (int i = 0; i < 128; i++) {
        row_ptr[base + i] = run;
        wcur[base + i] = run;
        run += cnt[base + i];
    }
    if (t == 255) row_ptr[NTOK * NTILE] = run;
}

__global__ void edge_scatter2_kernel(const int* __restrict__ src, const int* __restrict__ dst,
    const int* __restrict__ rel, int* __restrict__ wcur, int2* __restrict__ pairs, int E)
{
    int e = blockIdx.x * blockDim.x + threadIdx.x;
    if (e < E) {
        int d = dst[e];
        int pos = atomicAdd(&wcur[src[e] * NTILE + (d >> 7)], 1);
        pairs[pos] = make_int2(d, rel[e]);
    }
}

// ---------------- MFMA flash attention: split-K x8, head-major coalesced -------
// Grid (64, 8, SPLITS). Block: 1 head x 32 Q-rows x 256 tokens (2 tiles of 128),
// 256 thr (4 waves). Wave wv: q-rows (wv&1)*16 + c, col-half (wv>>1)*64.
// Typepair bias computed INSIDE QK^T via ext dims (K=64, 2 chained MFMAs).
#define QBLK 32
#define KBLK 128

__global__ __launch_bounds__(256) void attn_mfma3_kernel(
    const short* __restrict__ qh, const short* __restrict__ kh,
    const short* __restrict__ vt,
    const float* __restrict__ time_vec, const int* __restrict__ seed_ptr,
    const float* __restrict__ adj_rel_bias, const float* __restrict__ temp_bias,
    const int* __restrict__ row_ptr2, const int2* __restrict__ pairs2,
    float* __restrict__ Op_part, float2* __restrict__ ml_part)
{
    __shared__ __align__(16) short Q_lds[QBLK * LE];
    __shared__ __align__(16) short K_lds[KBLK * LE];     // reused as Opart[2][32][36] f32
    __shared__ __align__(16) short Vt_lds[DHEAD * 136];
    __shared__ __align__(16) unsigned int P32[QBLK * 68];
    __shared__ float tcol_s[KBLK];
    __shared__ float temp_h[21];
    __shared__ float adj_h[12];
    __shared__ float2 ml[2][QBLK];

    const int h  = blockIdx.y;
    const int n0 = blockIdx.x * QBLK;
    const int sblk = blockIdx.z;
    const int t  = threadIdx.x;
    const int wv = t >> 6, lane = t & 63, c = lane & 15, g = lane >> 4;
    const int rowblk  = (wv & 1) * 16;
    const int halfIdx = wv >> 1;
    const int colhalf = halfIdx * 64;
    const int seed = seed_ptr[0];
    const bool blockTemporal = (n0 < seed);
    const int gt0 = sblk * TPS;

    // ---- one-time staging: Q (32 x 64, fully coalesced), tables ----
    {
        int row = t >> 3, off = (t & 7) * 8;
        *(short8*)&Q_lds[row * LE + off] =
            *(const short8*)&qh[((size_t)h * NTOK + n0 + row) * EXTD + off];
    }
    if (t < 21)  temp_h[t] = temp_bias[t * HHEADS + h];
    if (t < 12)  adj_h[t] = adj_rel_bias[t * HHEADS + h];

    const int nrow = n0 + rowblk + c;
    const bool rowTemporal = (nrow < seed);
    const float tn = time_vec[nrow];

    // edge-CSR row-pointer prefetch for both tiles
    int2 rp01 = *(const int2*)&row_ptr2[nrow * NTILE + gt0];
    int  rp2  = row_ptr2[nrow * NTILE + gt0 + 2];

    // prefetch registers + fixed per-thread staging slots
    const int krow = t >> 3, koff = (t & 7) * 8;       // K: rows krow + 32i (4 chunks)
    const int vrow = t >> 4, voff = (t & 15) * 8;      // Vt: rows vrow, vrow+16
    short8 kr0, kr1, kr2, kr3, vr0, vr1;
    float tcr = 0.0f;

    auto LOADT = [&](int gt) {
        int m0 = gt * KBLK;
        const short* kp = &kh[((size_t)h * NTOK + m0 + krow) * EXTD + koff];
        kr0 = *(const short8*)kp;
        kr1 = *(const short8*)(kp + (size_t)32 * EXTD);
        kr2 = *(const short8*)(kp + (size_t)64 * EXTD);
        kr3 = *(const short8*)(kp + (size_t)96 * EXTD);
        const short* vp = &vt[(size_t)(h * 32 + vrow) * NTOK + m0 + voff];
        vr0 = *(const short8*)vp;
        vr1 = *(const short8*)(vp + (size_t)16 * NTOK);
        if (blockTemporal && t < 128) tcr = time_vec[m0 + t];
    };
    auto WRITET = [&]() {
        *(short8*)&K_lds[krow * LE + koff]        = kr0;
        *(short8*)&K_lds[(krow + 32) * LE + koff] = kr1;
        *(short8*)&K_lds[(krow + 64) * LE + koff] = kr2;
        *(short8*)&K_lds[(krow + 96) * LE + koff] = kr3;
        *(short8*)&Vt_lds[vrow * 136 + voff]        = vr0;
        *(short8*)&Vt_lds[(vrow + 16) * 136 + voff] = vr1;
        if (blockTemporal && t < 128) tcol_s[t] = tcr;
    };

    float m_run = -INFINITY, l_run = 0.0f;
    f32x4 oacc[2] = {{0,0,0,0},{0,0,0,0}};
    const f32x4 zf = {0.0f, 0.0f, 0.0f, 0.0f};

    LOADT(gt0);
    WRITET();

    for (int tile = 0; tile < TPS; ++tile) {
        __syncthreads();                       // staged tile visible
        if (tile + 1 < TPS) LOADT(gt0 + tile + 1);   // prefetch next (no wait)

        // ---- swapped QK^T with ext dims (K=64): score + typepair bias ----
        short8 qlo = *(const short8*)&Q_lds[(rowblk + c) * LE + g * 8];
        short8 qhi = *(const short8*)&Q_lds[(rowblk + c) * LE + 32 + g * 8];
        float vals[16];
        #pragma unroll
        for (int blk = 0; blk < 4; blk++) {
            const short* kb = &K_lds[(colhalf + blk * 16 + c) * LE];
            short8 klo = *(const short8*)(kb + g * 8);
            short8 khi = *(const short8*)(kb + 32 + g * 8);
            f32x4 acc = __builtin_amdgcn_mfma_f32_16x16x32_bf16(klo, qlo, zf, 0, 0, 0);
            acc = __builtin_amdgcn_mfma_f32_16x16x32_bf16(khi, qhi, acc, 0, 0, 0);
            #pragma unroll
            for (int reg = 0; reg < 4; reg++) vals[blk * 4 + reg] = acc[reg];
        }

        // ---- temporal bias (rows < seed only) ----
        if (rowTemporal) {
            #pragma unroll
            for (int blk = 0; blk < 4; blk++) {
                #pragma unroll
                for (int reg = 0; reg < 4; reg++) {
                    float dt = tcol_s[colhalf + blk * 16 + g * 4 + reg] - tn;
                    float ab = fabsf(dt) + 1e-6f;
                    float sg = (dt > 0.0f) ? 1.0f : ((dt < 0.0f) ? -1.0f : 0.0f);
                    float sl = sg * log1pf(ab);
                    sl = fminf(fmaxf(sl, -5.0f), 5.0f);
                    float norm = (sl + 5.0f) * (1.0f / (10.0f + 1e-9f));
                    int bidx = (int)floorf(norm * 20.0f);
                    bidx = min(max(bidx, 0), 20);
                    vals[blk * 4 + reg] += temp_h[bidx];
                }
            }
        }
        // ---- sparse edge bias: prefetched row-ptr ranges ----
        {
            int e0 = (tile == 0) ? rp01.x : rp01.y;
            int e1 = (tile == 0) ? rp01.y : rp2;
            for (int e = e0; e < e1; ++e) {
                int2 pr = pairs2[e];
                int dloc = pr.x & 127;
                if ((dloc >> 6) == halfIdx) {
                    int ml64 = dloc & 63;
                    if (((ml64 >> 2) & 3) == g) {
                        float ab = adj_h[pr.y];
                        int li = (ml64 >> 4) * 4 + (ml64 & 3);
                        #pragma unroll
                        for (int i = 0; i < 16; i++) vals[i] += (i == li) ? ab : 0.0f;
                    }
                }
            }
        }

        // ---- online softmax, lane-local row; reduce over 4 g-lanes ----
        float tmax = vals[0];
        #pragma unroll
        for (int i = 1; i < 16; i++) tmax = fmaxf(tmax, vals[i]);
        tmax = fmaxf(tmax, __shfl_xor(tmax, 16));
        tmax = fmaxf(tmax, __shfl_xor(tmax, 32));
        float m_new = fmaxf(m_run, tmax);
        float psum = 0.0f;
        #pragma unroll
        for (int i = 0; i < 16; i++) { vals[i] = __expf(vals[i] - m_new); psum += vals[i]; }
        psum += __shfl_xor(psum, 16);
        psum += __shfl_xor(psum, 32);
        float scale = __expf(m_run - m_new);
        m_run = m_new;
        l_run = l_run * scale + psum;

        // ---- pack P (bf16 pairs); same-wave consume, no barrier ----
        #pragma unroll
        for (int blk = 0; blk < 4; blk++) {
            #pragma unroll
            for (int r = 0; r < 2; r++) {
                unsigned lo = (unsigned short)f2bf(vals[blk * 4 + 2 * r]);
                unsigned hi = (unsigned short)f2bf(vals[blk * 4 + 2 * r + 1]);
                P32[(rowblk + c) * 68 + halfIdx * 32 + blk * 8 + g * 2 + r] = lo | (hi << 16);
            }
        }

        // ---- PV: rescale O, accumulate over this wave's 64-col half ----
        float scr[4];
        #pragma unroll
        for (int reg = 0; reg < 4; reg++) scr[reg] = __shfl(scale, 4 * g + reg);
        #pragma unroll
        for (int dblk = 0; dblk < 2; dblk++)
            #pragma unroll
            for (int reg = 0; reg < 4; reg++) oacc[dblk][reg] *= scr[reg];
        #pragma unroll
        for (int kc = 0; kc < 2; kc++) {
            short8 pa = *(const short8*)&P32[(rowblk + c) * 68 + halfIdx * 32 + kc * 16 + g * 4];
            #pragma unroll
            for (int dblk = 0; dblk < 2; dblk++) {
                short8 vb = *(const short8*)&Vt_lds[(dblk * 16 + c) * 136 + colhalf + kc * 32 + g * 8];
                oacc[dblk] = __builtin_amdgcn_mfma_f32_16x16x32_bf16(pa, vb, oacc[dblk], 0, 0, 0);
            }
        }

        __syncthreads();                       // all LDS reads of this tile done
        if (tile + 1 < TPS) WRITET();          // stage next tile
    }

    // ---- endgame: merge the two col-half partials, write split partial ----
    __syncthreads();
    if (lane < 16) ml[halfIdx][rowblk + lane] = make_float2(m_run, l_run);
    __syncthreads();

    float* Op = (float*)K_lds;   // [2][32][36]
    #pragma unroll
    for (int reg = 0; reg < 4; reg++) {
        int rw = rowblk + 4 * g + reg;
        float2 a0 = ml[0][rw], a1 = ml[1][rw];
        float mm = fmaxf(a0.x, a1.x);
        float wh = __expf((halfIdx == 0 ? a0.x : a1.x) - mm);
        Op[halfIdx * 32 * 36 + rw * 36 + c]      = oacc[0][reg] * wh;
        Op[halfIdx * 32 * 36 + rw * 36 + 16 + c] = oacc[1][reg] * wh;
    }
    __syncthreads();

    {
        int row = t >> 3, d0 = (t & 7) * 4;
        float2 a0 = ml[0][row], a1 = ml[1][row];
        float mm = fmaxf(a0.x, a1.x);
        float w0 = __expf(a0.x - mm), w1 = __expf(a1.x - mm);
        float lc = a0.y * w0 + a1.y * w1;
        float4 pa = *(const float4*)&Op[row * 36 + d0];
        float4 pb = *(const float4*)&Op[(32 + row) * 36 + d0];
        float4 sum;
        sum.x = pa.x + pb.x; sum.y = pa.y + pb.y;
        sum.z = pa.z + pb.z; sum.w = pa.w + pb.w;
        *(float4*)&Op_part[((size_t)sblk * NTOK + n0 + row) * CDIM + h * DHEAD + d0] = sum;
        if ((t & 7) == 0)
            ml_part[((size_t)sblk * NTOK + n0 + row) * HHEADS + h] = make_float2(mm, lc);
    }
}

// merge SPLITS partials -> o bf16. grid 2048, 256 thr (h = t>>5, d = t&31)
__global__ __launch_bounds__(256) void attn_reduce_kernel(
    const float* __restrict__ Op_part, const float2* __restrict__ ml_part,
    short* __restrict__ o)
{
    int row = blockIdx.x;
    int t = threadIdx.x;
    int h = t >> 5, d = t & 31;

    float2 a[SPLITS];
    float mm = -INFINITY;
    #pragma unroll
    for (int s = 0; s < SPLITS; s++) {
        a[s] = ml_part[((size_t)s * NTOK + row) * HHEADS + h];
        mm = fmaxf(mm, a[s].x);
    }
    float l = 0.0f, w[SPLITS];
    #pragma unroll
    for (int s = 0; s < SPLITS; s++) { w[s] = __expf(a[s].x - mm); l += a[s].y * w[s]; }
    float inv = 1.0f / l;
    size_t idx = (size_t)row * CDIM + h * DHEAD + d;
    float acc = 0.0f;
    #pragma unroll
    for (int s = 0; s < SPLITS; s++)
        acc += w[s] * Op_part[(size_t)s * NTOK * CDIM + idx];
    o[idx] = f2bf(acc * inv);
}

// ---------------- launch --------------------------------------------------------
extern "C" void kernel_launch(void* const* d_in, const int* in_sizes, int n_in,
                              void* d_out, int out_size, void* d_ws, size_t ws_size,
                              hipStream_t stream)
{
    (void)in_sizes; (void)n_in; (void)out_size; (void)ws_size;
    const float* X        = (const float*)d_in[0];
    const int* token_type = (const int*)d_in[1];
    const int* edge_src   = (const int*)d_in[2];
    const int* edge_dst   = (const int*)d_in[3];
    const int* edge_rel   = (const int*)d_in[4];
    const float* time_vec = (const float*)d_in[5];
    const int* seed_ptr   = (const int*)d_in[6];
    const float* Wq = (const float*)d_in[7];  const float* bq = (const float*)d_in[8];
    const float* Wk = (const float*)d_in[9];  const float* bk = (const float*)d_in[10];
    const float* Wv = (const float*)d_in[11]; const float* bv = (const float*)d_in[12];
    const float* Wo = (const float*)d_in[13]; const float* bo = (const float*)d_in[14];
    const float* ln1_g = (const float*)d_in[15]; const float* ln1_b = (const float*)d_in[16];
    const float* ln2_g = (const float*)d_in[17]; const float* ln2_b = (const float*)d_in[18];
    const float* W1 = (const float*)d_in[19]; const float* b1 = (const float*)d_in[20];
    const float* W2 = (const float*)d_in[21]; const float* b2 = (const float*)d_in[22];
    const float* adj_rel_bias  = (const float*)d_in[23];
    const float* typepair_bias = (const float*)d_in[24];
    const float* temp_bias     = (const float*)d_in[25];
    float* out = (float*)d_out;

    char* base = (char*)d_ws;
    size_t off = 0;
    auto alloc = [&](size_t bytes) { char* p = base + off; off += (bytes + 255) & ~(size_t)255; return p; };
    short* qh_bf   = (short*)alloc((size_t)HHEADS * NTOK * EXTD * 2);   // 2 MB
    short* kh_bf   = (short*)alloc((size_t)HHEADS * NTOK * EXTD * 2);
    short* vt_bf   = (short*)alloc((size_t)256 * NTOK * 2);
    short* h1_bf   = (short*)alloc((size_t)NTOK * 256 * 2);
    short* h2_bf   = (short*)alloc((size_t)NTOK * 256 * 2);
    short* o_bf    = (short*)alloc((size_t)NTOK * 256 * 2);
    short* mid_bf  = (short*)alloc((size_t)NTOK * 1024 * 2);
    float* xb      = (float*)alloc((size_t)NTOK * 256 * 4);
    short* wt_qkv  = (short*)alloc((size_t)768 * 256 * 2);
    short* wot     = (short*)alloc((size_t)256 * 256 * 2);
    short* w1t     = (short*)alloc((size_t)1024 * 256 * 2);
    short* w2t     = (short*)alloc((size_t)256 * 1024 * 2);
    int2*  pairs2  = (int2*)alloc((size_t)NEDGE * 8);
    int*   cnt2    = (int*)alloc((size_t)NTOK * NTILE * 4);
    int*   rowptr2 = (int*)alloc(((size_t)NTOK * NTILE + 1) * 4);
    int*   wcur2   = (int*)alloc((size_t)NTOK * NTILE * 4);
    float* Op_part = (float*)alloc((size_t)SPLITS * NTOK * CDIM * 4);   // 16 MB
    float2* ml_part = (float2*)alloc((size_t)SPLITS * NTOK * HHEADS * 8);

    // weight transposes + ext dims (independent of X / QKV outputs)
    transpose_all_kernel<<<192, 256, 0, stream>>>(Wq, Wk, Wv, Wo, W1, W2,
                                                  wt_qkv, wot, w1t, w2t);
    ext_build_kernel<<<64, 256, 0, stream>>>(token_type, typepair_bias, qh_bf, kh_bf);

    // LN1 -> bf16
    ln4_kernel<<<NTOK / 4, 256, 0, stream>>>(X, ln1_g, ln1_b, h1_bf);

    // fused QKV projection (q pre-scaled; head-major outputs; V transposed)
    gemm_qkv_kernel<<<dim3(12, 32), 256, 0, stream>>>(h1_bf, wt_qkv, bq, bk, bv,
                                                      qh_bf, kh_bf, vt_bf);

    // edge CSR bucketed by (src, dst>>7)
    hipMemsetAsync(cnt2, 0, NTOK * NTILE * sizeof(int), stream);
    edge_hist2_kernel<<<NEDGE / 256, 256, 0, stream>>>(edge_src, edge_dst, cnt2, NEDGE);
    edge_scan2_kernel<<<1, 256, 0, stream>>>(cnt2, rowptr2, wcur2);
    edge_scatter2_kernel<<<NEDGE / 256, 256, 0, stream>>>(edge_src, edge_dst, edge_rel, wcur2, pairs2, NEDGE);

    // fused MFMA attention (split-K x8) -> partials, then reduce -> o (bf16)
    attn_mfma3_kernel<<<dim3(NTOK / QBLK, HHEADS, SPLITS), 256, 0, stream>>>(
        qh_bf, kh_bf, vt_bf, time_vec, seed_ptr,
        adj_rel_bias, temp_bias, rowptr2, pairs2, Op_part, ml_part);
    attn_reduce_kernel<<<NTOK, 256, 0, stream>>>(Op_part, ml_part, o_bf);

    // x = X + o @ Wo + bo   (f32 out)
    gemm_bf16_kernel<2><<<dim3(4, 32), 256, 0, stream>>>(o_bf, wot, bo, X, xb, NTOK, 256, 256);

    // LN2 -> bf16
    ln4_kernel<<<NTOK / 4, 256, 0, stream>>>(xb, ln2_g, ln2_b, h2_bf);

    // FFN
    gemm_bf16_kernel<3><<<dim3(16, 32), 256, 0, stream>>>(h2_bf, w1t, b1, nullptr, mid_bf, NTOK, 1024, 256);
    gemm_bf16_kernel<2><<<dim3(4, 32), 256, 0, stream>>>(mid_bf, w2t, b2, xb, out, NTOK, 256, 1024);
}

// Round 10
// 169.263 us; speedup vs baseline: 1.0236x; 1.0236x over previous
//
#include <hip/hip_runtime.h>
#include <hip/hip_bf16.h>
#include <math.h>

#define NTOK 2048
#define CDIM 256
#define HHEADS 8
#define DHEAD 32
#define NEDGE 32768
#define NTILE 16          // edge-CSR buckets per row (dst >> 7), 128-wide
#define SPLITS 8
#define TPS 2             // tiles per split (KBLK=128)
#define EXTD 64           // ext head dim (32 qk + 8 bias + 24 zero)
#define LE 72             // ext LDS row stride (shorts)

typedef __attribute__((ext_vector_type(8))) short short8;
typedef __attribute__((ext_vector_type(4))) short short4v;
typedef __attribute__((ext_vector_type(4))) float f32x4;

static __device__ inline short f2bf(float f) {
    __hip_bfloat16 h = __float2bfloat16(f);
    return *reinterpret_cast<short*>(&h);
}
static __device__ inline float bf2f(short s) {
    unsigned int u = ((unsigned int)(unsigned short)s) << 16;
    return *reinterpret_cast<float*>(&u);
}

// ---------------- LayerNorm: 4 rows/block, one wave per row, shuffle-only ------
__global__ __launch_bounds__(256) void ln4_kernel(const float* __restrict__ X,
    const float* __restrict__ g, const float* __restrict__ b, short* __restrict__ out)
{
    int t = threadIdx.x;
    int wv = t >> 6, lane = t & 63;
    int row = blockIdx.x * 4 + wv;

    float4 x = *(const float4*)&X[(size_t)row * CDIM + lane * 4];
    float s = x.x + x.y + x.z + x.w;
    #pragma unroll
    for (int off = 1; off < 64; off <<= 1) s += __shfl_xor(s, off);
    float mu = s * (1.0f / CDIM);
    float4 d = { x.x - mu, x.y - mu, x.z - mu, x.w - mu };
    float s2 = d.x * d.x + d.y * d.y + d.z * d.z + d.w * d.w;
    #pragma unroll
    for (int off = 1; off < 64; off <<= 1) s2 += __shfl_xor(s2, off);
    float rsig = rsqrtf(s2 * (1.0f / CDIM) + 1e-5f);
    float4 gg = *(const float4*)&g[lane * 4];
    float4 bb = *(const float4*)&b[lane * 4];
    short o4[4];
    o4[0] = f2bf(d.x * rsig * gg.x + bb.x);
    o4[1] = f2bf(d.y * rsig * gg.y + bb.y);
    o4[2] = f2bf(d.z * rsig * gg.z + bb.z);
    o4[3] = f2bf(d.w * rsig * gg.w + bb.w);
    *(short4v*)&out[(size_t)row * CDIM + lane * 4] = *(short4v*)o4;
}

// ---------------- Transpose + bf16 convert tile helper -------------------------
static __device__ inline void transpose_tile_f32(const float* __restrict__ in,
    short* __restrict__ out, int K, int N, int k0, int n0, int t)
{
    __shared__ float tile[64][65];
    int r0 = t >> 4, c0 = (t & 15) * 4;
    #pragma unroll
    for (int i = 0; i < 4; i++) {
        int r = r0 + i * 16;
        float4 v = *(const float4*)(in + (size_t)(k0 + r) * N + n0 + c0);
        tile[r][c0 + 0] = v.x; tile[r][c0 + 1] = v.y;
        tile[r][c0 + 2] = v.z; tile[r][c0 + 3] = v.w;
    }
    __syncthreads();
    #pragma unroll
    for (int i = 0; i < 4; i++) {
        int nr = r0 + i * 16;
        short o4[4];
        #pragma unroll
        for (int j = 0; j < 4; j++) o4[j] = f2bf(tile[c0 + j][nr]);
        *(short4v*)(out + (size_t)(n0 + nr) * K + k0 + c0) = *(short4v*)o4;
    }
}

// ---------------- Prep: weight transposes + ext dims + cnt2 zero (one launch) --
// blocks 0..191: transposes; 192..255: ext_build; 256..287: zero cnt2.
__global__ __launch_bounds__(256) void prep_kernel(
    const float* __restrict__ Wq, const float* __restrict__ Wk,
    const float* __restrict__ Wv, const float* __restrict__ Wo,
    const float* __restrict__ W1, const float* __restrict__ W2,
    short* __restrict__ wt_qkv, short* __restrict__ wot,
    short* __restrict__ w1t, short* __restrict__ w2t,
    const int* __restrict__ token_type, const float* __restrict__ typepair_bias,
    short* __restrict__ qh, short* __restrict__ kh,
    int* __restrict__ cnt2)
{
    int b = blockIdx.x;
    int t = threadIdx.x;
    if (b < 192) {
        const float* src; short* dst; int K, N, bx, by;
        if (b < 64) {
            int m = b >> 4, r = b & 15;
            src = (m == 0) ? Wq : (m == 1) ? Wk : (m == 2) ? Wv : Wo;
            dst = (m == 0) ? wt_qkv : (m == 1) ? wt_qkv + 256 * 256
                : (m == 2) ? wt_qkv + 512 * 256 : wot;
            K = 256; N = 256; bx = r & 3; by = r >> 2;
        } else if (b < 128) {
            int r = b - 64; src = W1; dst = w1t; K = 256; N = 1024; bx = r & 15; by = r >> 4;
        } else {
            int r = b - 128; src = W2; dst = w2t; K = 1024; N = 256; bx = r & 3; by = r >> 2;
        }
        transpose_tile_f32(src, dst, K, N, by * 64, bx * 64, t);
    } else if (b < 256) {
        int idx = (b - 192) * 256 + t;     // (row, h)
        int row = idx >> 3, h = idx & 7;
        int tt = token_type[row];
        short qe[32], ke[32];
        #pragma unroll
        for (int j = 0; j < 32; j++) {
            if (j < 8) {
                qe[j] = f2bf(typepair_bias[(tt * 8 + j) * 8 + h]);
                ke[j] = (j == tt) ? (short)0x3F80 : (short)0;   // bf16 1.0
            } else { qe[j] = 0; ke[j] = 0; }
        }
        size_t base = ((size_t)h * NTOK + row) * EXTD + 32;
        #pragma unroll
        for (int k = 0; k < 4; k++) {
            *(short8*)&qh[base + k * 8] = *(short8*)&qe[k * 8];
            *(short8*)&kh[base + k * 8] = *(short8*)&ke[k * 8];
        }
    } else {
        cnt2[(b - 256) * 256 + t] = 0;     // 32 blocks x 256 = 8192... need 32768
        cnt2[(b - 256) * 256 + t + 8192] = 0;
        cnt2[(b - 256) * 256 + t + 16384] = 0;
        cnt2[(b - 256) * 256 + t + 24576] = 0;
    }
}

// ---------------- bf16 MFMA GEMM, 32x64 tile, BK=32, 256 thr -------------------
// A[M][K] bf16, Bt[N][K] bf16. EPI: 2 = f32 out + resid, 3 = GELU -> bf16.
template<int EPI>
__global__ __launch_bounds__(256) void gemm32_kernel(
    const short* __restrict__ A, const short* __restrict__ Bt,
    const float* __restrict__ bias, const float* __restrict__ resid,
    void* __restrict__ out_, int M, int N, int K)
{
    __shared__ short A_lds[32 * 40];
    __shared__ short B_lds[64 * 40];

    const int t = threadIdx.x;
    const int w = t >> 6, lane = t & 63, c = lane & 15, g = lane >> 4;
    const int row0 = blockIdx.y * 32, col0 = blockIdx.x * 64;
    const int srow = t >> 2, sk = (t & 3) * 8;

    f32x4 acc[2] = {};

    for (int k0 = 0; k0 < K; k0 += 32) {
        if (t < 128)
            *(short8*)&A_lds[srow * 40 + sk] = *(const short8*)&A[(size_t)(row0 + srow) * K + k0 + sk];
        *(short8*)&B_lds[srow * 40 + sk] = *(const short8*)&Bt[(size_t)(col0 + srow) * K + k0 + sk];
        __syncthreads();
        short8 af = *(const short8*)&A_lds[((w & 1) * 16 + c) * 40 + g * 8];
        #pragma unroll
        for (int nf = 0; nf < 2; nf++) {
            short8 bf = *(const short8*)&B_lds[((w >> 1) * 32 + nf * 16 + c) * 40 + g * 8];
            acc[nf] = __builtin_amdgcn_mfma_f32_16x16x32_bf16(af, bf, acc[nf], 0, 0, 0);
        }
        __syncthreads();
    }

    #pragma unroll
    for (int nf = 0; nf < 2; nf++) {
        #pragma unroll
        for (int reg = 0; reg < 4; reg++) {
            int row = row0 + (w & 1) * 16 + g * 4 + reg;
            int col = col0 + (w >> 1) * 32 + nf * 16 + c;
            float v = acc[nf][reg] + bias[col];
            if (EPI == 2) {
                ((float*)out_)[(size_t)row * N + col] = v + resid[(size_t)row * N + col];
            } else {
                v = 0.5f * v * (1.0f + erff(v * 0.70710678118654752f));
                ((short*)out_)[(size_t)row * N + col] = f2bf(v);
            }
        }
    }
}

// Fused QKV GEMM (32x64): q -> qh[h][row][0..31] (scaled), k -> kh, v -> vt
__global__ __launch_bounds__(256) void gemm32_qkv_kernel(
    const short* __restrict__ A, const short* __restrict__ Bt,
    const float* __restrict__ bq, const float* __restrict__ bk, const float* __restrict__ bv,
    short* __restrict__ qh, short* __restrict__ kh, short* __restrict__ vt)
{
    const int K = CDIM;
    __shared__ short A_lds[32 * 40];
    __shared__ short B_lds[64 * 40];

    const int t = threadIdx.x;
    const int w = t >> 6, lane = t & 63, c = lane & 15, g = lane >> 4;
    const int row0 = blockIdx.y * 32, col0 = blockIdx.x * 64;
    const int srow = t >> 2, sk = (t & 3) * 8;

    f32x4 acc[2] = {};

    for (int k0 = 0; k0 < K; k0 += 32) {
        if (t < 128)
            *(short8*)&A_lds[srow * 40 + sk] = *(const short8*)&A[(size_t)(row0 + srow) * K + k0 + sk];
        *(short8*)&B_lds[srow * 40 + sk] = *(const short8*)&Bt[(size_t)(col0 + srow) * K + k0 + sk];
        __syncthreads();
        short8 af = *(const short8*)&A_lds[((w & 1) * 16 + c) * 40 + g * 8];
        #pragma unroll
        for (int nf = 0; nf < 2; nf++) {
            short8 bf = *(const short8*)&B_lds[((w >> 1) * 32 + nf * 16 + c) * 40 + g * 8];
            acc[nf] = __builtin_amdgcn_mfma_f32_16x16x32_bf16(af, bf, acc[nf], 0, 0, 0);
        }
        __syncthreads();
    }

    const int region = col0 >> 8;           // 0=q, 1=k, 2=v
    const int colr0 = col0 & 255;
    const float* bias = (region == 0) ? bq : (region == 1) ? bk : bv;
    #pragma unroll
    for (int nf = 0; nf < 2; nf++) {
        #pragma unroll
        for (int reg = 0; reg < 4; reg++) {
            int row = row0 + (w & 1) * 16 + g * 4 + reg;
            int col = colr0 + (w >> 1) * 32 + nf * 16 + c;
            float v = acc[nf][reg] + bias[col];
            if (region == 0) v *= 0.17677669529663687f;   // 1/sqrt(32)
            short bb = f2bf(v);
            size_t hidx = ((size_t)(col >> 5) * NTOK + row) * EXTD + (col & 31);
            if (region == 0)      qh[hidx] = bb;
            else if (region == 1) kh[hidx] = bb;
            else                  vt[(size_t)col * NTOK + row] = bb;   // V^T direct
        }
    }
}

// ---------------- Edge CSR build, bucketed by (src, dst>>7) --------------------
__global__ void edge_hist2_kernel(const int* __restrict__ src, const int* __restrict__ dst,
    int* __restrict__ cnt, int E)
{
    int e = blockIdx.x * blockDim.x + threadIdx.x;
    if (e < E) atomicAdd(&cnt[src[e] * NTILE + (dst[e] >> 7)], 1);
}

__global__ __launch_bounds__(256) void edge_scan2_kernel(const int* __restrict__ cnt,
    int* __restrict__ row_ptr, int* __restrict__ wcur)
{
    __shared__ int sums[256];
    int t = threadIdx.x;
    int base = t * 128;
    int s = 0;
    for (int i = 0; i < 128; i++) s += cnt[base + i];
    sums[t] = s;
    __syncthreads();
    for (int off = 1; off < 256; off <<= 1) {
        int v = (t >= off) ? sums[t - off] : 0;
        __syncthreads();
        sums[t] += v;
        __syncthreads();
    }
    int run = (t == 0) ? 0 : sums[t - 1];
    for (int i = 0; i < 128; i++) {
        row_ptr[base + i] = run;
        wcur[base + i] = run;
        run += cnt[base + i];
    }
    if (t == 255) row_ptr[NTOK * NTILE] = run;
}

__global__ void edge_scatter2_kernel(const int* __restrict__ src, const int* __restrict__ dst,
    const int* __restrict__ rel, int* __restrict__ wcur, int2* __restrict__ pairs, int E)
{
    int e = blockIdx.x * blockDim.x + threadIdx.x;
    if (e < E) {
        int d = dst[e];
        int pos = atomicAdd(&wcur[src[e] * NTILE + (d >> 7)], 1);
        pairs[pos] = make_int2(d, rel[e]);
    }
}

// ---------------- MFMA flash attention: split-K x8, head-major coalesced -------
#define QBLK 32
#define KBLK 128

__global__ __launch_bounds__(256) void attn_mfma3_kernel(
    const short* __restrict__ qh, const short* __restrict__ kh,
    const short* __restrict__ vt,
    const float* __restrict__ time_vec, const int* __restrict__ seed_ptr,
    const float* __restrict__ adj_rel_bias, const float* __restrict__ temp_bias,
    const int* __restrict__ row_ptr2, const int2* __restrict__ pairs2,
    float* __restrict__ Op_part, float2* __restrict__ ml_part)
{
    __shared__ __align__(16) short Q_lds[QBLK * LE];
    __shared__ __align__(16) short K_lds[KBLK * LE];     // reused as Opart[2][32][36] f32
    __shared__ __align__(16) short Vt_lds[DHEAD * 136];
    __shared__ __align__(16) unsigned int P32[QBLK * 68];
    __shared__ float tcol_s[KBLK];
    __shared__ float temp_h[21];
    __shared__ float adj_h[12];
    __shared__ float2 ml[2][QBLK];

    const int h  = blockIdx.y;
    const int n0 = blockIdx.x * QBLK;
    const int sblk = blockIdx.z;
    const int t  = threadIdx.x;
    const int wv = t >> 6, lane = t & 63, c = lane & 15, g = lane >> 4;
    const int rowblk  = (wv & 1) * 16;
    const int halfIdx = wv >> 1;
    const int colhalf = halfIdx * 64;
    const int seed = seed_ptr[0];
    const bool blockTemporal = (n0 < seed);
    const int gt0 = sblk * TPS;

    // ---- one-time staging: Q (32 x 64, fully coalesced), tables ----
    {
        int row = t >> 3, off = (t & 7) * 8;
        *(short8*)&Q_lds[row * LE + off] =
            *(const short8*)&qh[((size_t)h * NTOK + n0 + row) * EXTD + off];
    }
    if (t < 21)  temp_h[t] = temp_bias[t * HHEADS + h];
    if (t < 12)  adj_h[t] = adj_rel_bias[t * HHEADS + h];

    const int nrow = n0 + rowblk + c;
    const bool rowTemporal = (nrow < seed);
    const float tn = time_vec[nrow];

    // edge-CSR row-pointer prefetch for both tiles
    int2 rp01 = *(const int2*)&row_ptr2[nrow * NTILE + gt0];
    int  rp2  = row_ptr2[nrow * NTILE + gt0 + 2];

    // prefetch registers + fixed per-thread staging slots
    const int krow = t >> 3, koff = (t & 7) * 8;       // K: rows krow + 32i (4 chunks)
    const int vrow = t >> 4, voff = (t & 15) * 8;      // Vt: rows vrow, vrow+16
    short8 kr0, kr1, kr2, kr3, vr0, vr1;
    float tcr = 0.0f;

    auto LOADT = [&](int gt) {
        int m0 = gt * KBLK;
        const short* kp = &kh[((size_t)h * NTOK + m0 + krow) * EXTD + koff];
        kr0 = *(const short8*)kp;
        kr1 = *(const short8*)(kp + (size_t)32 * EXTD);
        kr2 = *(const short8*)(kp + (size_t)64 * EXTD);
        kr3 = *(const short8*)(kp + (size_t)96 * EXTD);
        const short* vp = &vt[(size_t)(h * 32 + vrow) * NTOK + m0 + voff];
        vr0 = *(const short8*)vp;
        vr1 = *(const short8*)(vp + (size_t)16 * NTOK);
        if (blockTemporal && t < 128) tcr = time_vec[m0 + t];
    };
    auto WRITET = [&]() {
        *(short8*)&K_lds[krow * LE + koff]        = kr0;
        *(short8*)&K_lds[(krow + 32) * LE + koff] = kr1;
        *(short8*)&K_lds[(krow + 64) * LE + koff] = kr2;
        *(short8*)&K_lds[(krow + 96) * LE + koff] = kr3;
        *(short8*)&Vt_lds[vrow * 136 + voff]        = vr0;
        *(short8*)&Vt_lds[(vrow + 16) * 136 + voff] = vr1;
        if (blockTemporal && t < 128) tcol_s[t] = tcr;
    };

    float m_run = -INFINITY, l_run = 0.0f;
    f32x4 oacc[2] = {{0,0,0,0},{0,0,0,0}};
    const f32x4 zf = {0.0f, 0.0f, 0.0f, 0.0f};

    LOADT(gt0);
    WRITET();

    for (int tile = 0; tile < TPS; ++tile) {
        __syncthreads();                       // staged tile visible
        if (tile + 1 < TPS) LOADT(gt0 + tile + 1);   // prefetch next (no wait)

        // ---- swapped QK^T with ext dims (K=64): score + typepair bias ----
        short8 qlo = *(const short8*)&Q_lds[(rowblk + c) * LE + g * 8];
        short8 qhi = *(const short8*)&Q_lds[(rowblk + c) * LE + 32 + g * 8];
        float vals[16];
        #pragma unroll
        for (int blk = 0; blk < 4; blk++) {
            const short* kb = &K_lds[(colhalf + blk * 16 + c) * LE];
            short8 klo = *(const short8*)(kb + g * 8);
            short8 khi = *(const short8*)(kb + 32 + g * 8);
            f32x4 acc = __builtin_amdgcn_mfma_f32_16x16x32_bf16(klo, qlo, zf, 0, 0, 0);
            acc = __builtin_amdgcn_mfma_f32_16x16x32_bf16(khi, qhi, acc, 0, 0, 0);
            #pragma unroll
            for (int reg = 0; reg < 4; reg++) vals[blk * 4 + reg] = acc[reg];
        }

        // ---- temporal bias (rows < seed only) ----
        if (rowTemporal) {
            #pragma unroll
            for (int blk = 0; blk < 4; blk++) {
                #pragma unroll
                for (int reg = 0; reg < 4; reg++) {
                    float dt = tcol_s[colhalf + blk * 16 + g * 4 + reg] - tn;
                    float ab = fabsf(dt) + 1e-6f;
                    float sg = (dt > 0.0f) ? 1.0f : ((dt < 0.0f) ? -1.0f : 0.0f);
                    float sl = sg * log1pf(ab);
                    sl = fminf(fmaxf(sl, -5.0f), 5.0f);
                    float norm = (sl + 5.0f) * (1.0f / (10.0f + 1e-9f));
                    int bidx = (int)floorf(norm * 20.0f);
                    bidx = min(max(bidx, 0), 20);
                    vals[blk * 4 + reg] += temp_h[bidx];
                }
            }
        }
        // ---- sparse edge bias: prefetched row-ptr ranges ----
        {
            int e0 = (tile == 0) ? rp01.x : rp01.y;
            int e1 = (tile == 0) ? rp01.y : rp2;
            for (int e = e0; e < e1; ++e) {
                int2 pr = pairs2[e];
                int dloc = pr.x & 127;
                if ((dloc >> 6) == halfIdx) {
                    int ml64 = dloc & 63;
                    if (((ml64 >> 2) & 3) == g) {
                        float ab = adj_h[pr.y];
                        int li = (ml64 >> 4) * 4 + (ml64 & 3);
                        #pragma unroll
                        for (int i = 0; i < 16; i++) vals[i] += (i == li) ? ab : 0.0f;
                    }
                }
            }
        }

        // ---- online softmax, lane-local row; reduce over 4 g-lanes ----
        float tmax = vals[0];
        #pragma unroll
        for (int i = 1; i < 16; i++) tmax = fmaxf(tmax, vals[i]);
        tmax = fmaxf(tmax, __shfl_xor(tmax, 16));
        tmax = fmaxf(tmax, __shfl_xor(tmax, 32));
        float m_new = fmaxf(m_run, tmax);
        float psum = 0.0f;
        #pragma unroll
        for (int i = 0; i < 16; i++) { vals[i] = __expf(vals[i] - m_new); psum += vals[i]; }
        psum += __shfl_xor(psum, 16);
        psum += __shfl_xor(psum, 32);
        float scale = __expf(m_run - m_new);
        m_run = m_new;
        l_run = l_run * scale + psum;

        // ---- pack P (bf16 pairs); same-wave consume, no barrier ----
        #pragma unroll
        for (int blk = 0; blk < 4; blk++) {
            #pragma unroll
            for (int r = 0; r < 2; r++) {
                unsigned lo = (unsigned short)f2bf(vals[blk * 4 + 2 * r]);
                unsigned hi = (unsigned short)f2bf(vals[blk * 4 + 2 * r + 1]);
                P32[(rowblk + c) * 68 + halfIdx * 32 + blk * 8 + g * 2 + r] = lo | (hi << 16);
            }
        }

        // ---- PV: rescale O, accumulate over this wave's 64-col half ----
        float scr[4];
        #pragma unroll
        for (int reg = 0; reg < 4; reg++) scr[reg] = __shfl(scale, 4 * g + reg);
        #pragma unroll
        for (int dblk = 0; dblk < 2; dblk++)
            #pragma unroll
            for (int reg = 0; reg < 4; reg++) oacc[dblk][reg] *= scr[reg];
        #pragma unroll
        for (int kc = 0; kc < 2; kc++) {
            short8 pa = *(const short8*)&P32[(rowblk + c) * 68 + halfIdx * 32 + kc * 16 + g * 4];
            #pragma unroll
            for (int dblk = 0; dblk < 2; dblk++) {
                short8 vb = *(const short8*)&Vt_lds[(dblk * 16 + c) * 136 + colhalf + kc * 32 + g * 8];
                oacc[dblk] = __builtin_amdgcn_mfma_f32_16x16x32_bf16(pa, vb, oacc[dblk], 0, 0, 0);
            }
        }

        __syncthreads();                       // all LDS reads of this tile done
        if (tile + 1 < TPS) WRITET();          // stage next tile
    }

    // ---- endgame: merge the two col-half partials, write split partial ----
    __syncthreads();
    if (lane < 16) ml[halfIdx][rowblk + lane] = make_float2(m_run, l_run);
    __syncthreads();

    float* Op = (float*)K_lds;   // [2][32][36]
    #pragma unroll
    for (int reg = 0; reg < 4; reg++) {
        int rw = rowblk + 4 * g + reg;
        float2 a0 = ml[0][rw], a1 = ml[1][rw];
        float mm = fmaxf(a0.x, a1.x);
        float wh = __expf((halfIdx == 0 ? a0.x : a1.x) - mm);
        Op[halfIdx * 32 * 36 + rw * 36 + c]      = oacc[0][reg] * wh;
        Op[halfIdx * 32 * 36 + rw * 36 + 16 + c] = oacc[1][reg] * wh;
    }
    __syncthreads();

    {
        int row = t >> 3, d0 = (t & 7) * 4;
        float2 a0 = ml[0][row], a1 = ml[1][row];
        float mm = fmaxf(a0.x, a1.x);
        float w0 = __expf(a0.x - mm), w1 = __expf(a1.x - mm);
        float lc = a0.y * w0 + a1.y * w1;
        float4 pa = *(const float4*)&Op[row * 36 + d0];
        float4 pb = *(const float4*)&Op[(32 + row) * 36 + d0];
        float4 sum;
        sum.x = pa.x + pb.x; sum.y = pa.y + pb.y;
        sum.z = pa.z + pb.z; sum.w = pa.w + pb.w;
        *(float4*)&Op_part[((size_t)sblk * NTOK + n0 + row) * CDIM + h * DHEAD + d0] = sum;
        if ((t & 7) == 0)
            ml_part[((size_t)sblk * NTOK + n0 + row) * HHEADS + h] = make_float2(mm, lc);
    }
}

// merge SPLITS partials -> o bf16. grid 2048, 256 thr (h = t>>5, d = t&31)
__global__ __launch_bounds__(256) void attn_reduce_kernel(
    const float* __restrict__ Op_part, const float2* __restrict__ ml_part,
    short* __restrict__ o)
{
    int row = blockIdx.x;
    int t = threadIdx.x;
    int h = t >> 5, d = t & 31;

    float2 a[SPLITS];
    float mm = -INFINITY;
    #pragma unroll
    for (int s = 0; s < SPLITS; s++) {
        a[s] = ml_part[((size_t)s * NTOK + row) * HHEADS + h];
        mm = fmaxf(mm, a[s].x);
    }
    float l = 0.0f, w[SPLITS];
    #pragma unroll
    for (int s = 0; s < SPLITS; s++) { w[s] = __expf(a[s].x - mm); l += a[s].y * w[s]; }
    float inv = 1.0f / l;
    size_t idx = (size_t)row * CDIM + h * DHEAD + d;
    float acc = 0.0f;
    #pragma unroll
    for (int s = 0; s < SPLITS; s++)
        acc += w[s] * Op_part[(size_t)s * NTOK * CDIM + idx];
    o[idx] = f2bf(acc * inv);
}

// ---------------- launch --------------------------------------------------------
extern "C" void kernel_launch(void* const* d_in, const int* in_sizes, int n_in,
                              void* d_out, int out_size, void* d_ws, size_t ws_size,
                              hipStream_t stream)
{
    (void)in_sizes; (void)n_in; (void)out_size; (void)ws_size;
    const float* X        = (const float*)d_in[0];
    const int* token_type = (const int*)d_in[1];
    const int* edge_src   = (const int*)d_in[2];
    const int* edge_dst   = (const int*)d_in[3];
    const int* edge_rel   = (const int*)d_in[4];
    const float* time_vec = (const float*)d_in[5];
    const int* seed_ptr   = (const int*)d_in[6];
    const float* Wq = (const float*)d_in[7];  const float* bq = (const float*)d_in[8];
    const float* Wk = (const float*)d_in[9];  const float* bk = (const float*)d_in[10];
    const float* Wv = (const float*)d_in[11]; const float* bv = (const float*)d_in[12];
    const float* Wo = (const float*)d_in[13]; const float* bo = (const float*)d_in[14];
    const float* ln1_g = (const float*)d_in[15]; const float* ln1_b = (const float*)d_in[16];
    const float* ln2_g = (const float*)d_in[17]; const float* ln2_b = (const float*)d_in[18];
    const float* W1 = (const float*)d_in[19]; const float* b1 = (const float*)d_in[20];
    const float* W2 = (const float*)d_in[21]; const float* b2 = (const float*)d_in[22];
    const float* adj_rel_bias  = (const float*)d_in[23];
    const float* typepair_bias = (const float*)d_in[24];
    const float* temp_bias     = (const float*)d_in[25];
    float* out = (float*)d_out;

    char* base = (char*)d_ws;
    size_t off = 0;
    auto alloc = [&](size_t bytes) { char* p = base + off; off += (bytes + 255) & ~(size_t)255; return p; };
    short* qh_bf   = (short*)alloc((size_t)HHEADS * NTOK * EXTD * 2);   // 2 MB
    short* kh_bf   = (short*)alloc((size_t)HHEADS * NTOK * EXTD * 2);
    short* vt_bf   = (short*)alloc((size_t)256 * NTOK * 2);
    short* h1_bf   = (short*)alloc((size_t)NTOK * 256 * 2);
    short* h2_bf   = (short*)alloc((size_t)NTOK * 256 * 2);
    short* o_bf    = (short*)alloc((size_t)NTOK * 256 * 2);
    short* mid_bf  = (short*)alloc((size_t)NTOK * 1024 * 2);
    float* xb      = (float*)alloc((size_t)NTOK * 256 * 4);
    short* wt_qkv  = (short*)alloc((size_t)768 * 256 * 2);
    short* wot     = (short*)alloc((size_t)256 * 256 * 2);
    short* w1t     = (short*)alloc((size_t)1024 * 256 * 2);
    short* w2t     = (short*)alloc((size_t)256 * 1024 * 2);
    int2*  pairs2  = (int2*)alloc((size_t)NEDGE * 8);
    int*   cnt2    = (int*)alloc((size_t)NTOK * NTILE * 4);
    int*   rowptr2 = (int*)alloc(((size_t)NTOK * NTILE + 1) * 4);
    int*   wcur2   = (int*)alloc((size_t)NTOK * NTILE * 4);
    float* Op_part = (float*)alloc((size_t)SPLITS * NTOK * CDIM * 4);   // 16 MB
    float2* ml_part = (float2*)alloc((size_t)SPLITS * NTOK * HHEADS * 8);

    // prep: weight transposes + ext dims + cnt2 zeroing (one launch)
    prep_kernel<<<288, 256, 0, stream>>>(Wq, Wk, Wv, Wo, W1, W2,
                                         wt_qkv, wot, w1t, w2t,
                                         token_type, typepair_bias,
                                         qh_bf, kh_bf, cnt2);

    // edge CSR bucketed by (src, dst>>7)
    edge_hist2_kernel<<<NEDGE / 256, 256, 0, stream>>>(edge_src, edge_dst, cnt2, NEDGE);
    edge_scan2_kernel<<<1, 256, 0, stream>>>(cnt2, rowptr2, wcur2);
    edge_scatter2_kernel<<<NEDGE / 256, 256, 0, stream>>>(edge_src, edge_dst, edge_rel, wcur2, pairs2, NEDGE);

    // LN1 -> bf16
    ln4_kernel<<<NTOK / 4, 256, 0, stream>>>(X, ln1_g, ln1_b, h1_bf);

    // fused QKV projection (q pre-scaled; head-major outputs; V transposed)
    gemm32_qkv_kernel<<<dim3(12, 64), 256, 0, stream>>>(h1_bf, wt_qkv, bq, bk, bv,
                                                        qh_bf, kh_bf, vt_bf);

    // fused MFMA attention (split-K x8) -> partials, then reduce -> o (bf16)
    attn_mfma3_kernel<<<dim3(NTOK / QBLK, HHEADS, SPLITS), 256, 0, stream>>>(
        qh_bf, kh_bf, vt_bf, time_vec, seed_ptr,
        adj_rel_bias, temp_bias, rowptr2, pairs2, Op_part, ml_part);
    attn_reduce_kernel<<<NTOK, 256, 0, stream>>>(Op_part, ml_part, o_bf);

    // x = X + o @ Wo + bo   (f32 out)
    gemm32_kernel<2><<<dim3(4, 64), 256, 0, stream>>>(o_bf, wot, bo, X, xb, NTOK, 256, 256);

    // LN2 -> bf16
    ln4_kernel<<<NTOK / 4, 256, 0, stream>>>(xb, ln2_g, ln2_b, h2_bf);

    // FFN
    gemm32_kernel<3><<<dim3(16, 64), 256, 0, stream>>>(h2_bf, w1t, b1, nullptr, mid_bf, NTOK, 1024, 256);
    gemm32_kernel<2><<<dim3(4, 64), 256, 0, stream>>>(mid_bf, w2t, b2, xb, out, NTOK, 256, 1024);
}

// Round 11
// 151.894 us; speedup vs baseline: 1.1407x; 1.1144x over previous
//
#include <hip/hip_runtime.h>
#include <hip/hip_bf16.h>
#include <math.h>

#define NTOK 2048
#define CDIM 256
#define HHEADS 8
#define DHEAD 32
#define NEDGE 32768
#define NTILE 16          // edge-CSR buckets per row (dst >> 7), 128-wide
#define SPLITS 8
#define TPS 2             // tiles per split (KBLK=128) [fallback path]
#define EXTD 64           // ext head dim (32 qk + 8 bias + 24 zero)
#define LE 72             // ext LDS row stride (shorts)

typedef __attribute__((ext_vector_type(8))) short short8;
typedef __attribute__((ext_vector_type(4))) short short4v;
typedef __attribute__((ext_vector_type(4))) float f32x4;

static __device__ inline short f2bf(float f) {
    __hip_bfloat16 h = __float2bfloat16(f);
    return *reinterpret_cast<short*>(&h);
}
static __device__ inline float bf2f(short s) {
    unsigned int u = ((unsigned int)(unsigned short)s) << 16;
    return *reinterpret_cast<float*>(&u);
}

// ---------------- LayerNorm: 4 rows/block, one wave per row, shuffle-only ------
__global__ __launch_bounds__(256) void ln4_kernel(const float* __restrict__ X,
    const float* __restrict__ g, const float* __restrict__ b, short* __restrict__ out)
{
    int t = threadIdx.x;
    int wv = t >> 6, lane = t & 63;
    int row = blockIdx.x * 4 + wv;

    float4 x = *(const float4*)&X[(size_t)row * CDIM + lane * 4];
    float s = x.x + x.y + x.z + x.w;
    #pragma unroll
    for (int off = 1; off < 64; off <<= 1) s += __shfl_xor(s, off);
    float mu = s * (1.0f / CDIM);
    float4 d = { x.x - mu, x.y - mu, x.z - mu, x.w - mu };
    float s2 = d.x * d.x + d.y * d.y + d.z * d.z + d.w * d.w;
    #pragma unroll
    for (int off = 1; off < 64; off <<= 1) s2 += __shfl_xor(s2, off);
    float rsig = rsqrtf(s2 * (1.0f / CDIM) + 1e-5f);
    float4 gg = *(const float4*)&g[lane * 4];
    float4 bb = *(const float4*)&b[lane * 4];
    short o4[4];
    o4[0] = f2bf(d.x * rsig * gg.x + bb.x);
    o4[1] = f2bf(d.y * rsig * gg.y + bb.y);
    o4[2] = f2bf(d.z * rsig * gg.z + bb.z);
    o4[3] = f2bf(d.w * rsig * gg.w + bb.w);
    *(short4v*)&out[(size_t)row * CDIM + lane * 4] = *(short4v*)o4;
}

// ---------------- Transpose + bf16 convert tile helper -------------------------
static __device__ inline void transpose_tile_f32(const float* __restrict__ in,
    short* __restrict__ out, int K, int N, int k0, int n0, int t)
{
    __shared__ float tile[64][65];
    int r0 = t >> 4, c0 = (t & 15) * 4;
    #pragma unroll
    for (int i = 0; i < 4; i++) {
        int r = r0 + i * 16;
        float4 v = *(const float4*)(in + (size_t)(k0 + r) * N + n0 + c0);
        tile[r][c0 + 0] = v.x; tile[r][c0 + 1] = v.y;
        tile[r][c0 + 2] = v.z; tile[r][c0 + 3] = v.w;
    }
    __syncthreads();
    #pragma unroll
    for (int i = 0; i < 4; i++) {
        int nr = r0 + i * 16;
        short o4[4];
        #pragma unroll
        for (int j = 0; j < 4; j++) o4[j] = f2bf(tile[c0 + j][nr]);
        *(short4v*)(out + (size_t)(n0 + nr) * K + k0 + c0) = *(short4v*)o4;
    }
}

// ---------------- Prep: weight transposes + ext dims + cnt2 zero (one launch) --
__global__ __launch_bounds__(256) void prep_kernel(
    const float* __restrict__ Wq, const float* __restrict__ Wk,
    const float* __restrict__ Wv, const float* __restrict__ Wo,
    const float* __restrict__ W1, const float* __restrict__ W2,
    short* __restrict__ wt_qkv, short* __restrict__ wot,
    short* __restrict__ w1t, short* __restrict__ w2t,
    const int* __restrict__ token_type, const float* __restrict__ typepair_bias,
    short* __restrict__ qh, short* __restrict__ kh,
    int* __restrict__ cnt2)
{
    int b = blockIdx.x;
    int t = threadIdx.x;
    if (b < 192) {
        const float* src; short* dst; int K, N, bx, by;
        if (b < 64) {
            int m = b >> 4, r = b & 15;
            src = (m == 0) ? Wq : (m == 1) ? Wk : (m == 2) ? Wv : Wo;
            dst = (m == 0) ? wt_qkv : (m == 1) ? wt_qkv + 256 * 256
                : (m == 2) ? wt_qkv + 512 * 256 : wot;
            K = 256; N = 256; bx = r & 3; by = r >> 2;
        } else if (b < 128) {
            int r = b - 64; src = W1; dst = w1t; K = 256; N = 1024; bx = r & 15; by = r >> 4;
        } else {
            int r = b - 128; src = W2; dst = w2t; K = 1024; N = 256; bx = r & 3; by = r >> 2;
        }
        transpose_tile_f32(src, dst, K, N, by * 64, bx * 64, t);
    } else if (b < 256) {
        int idx = (b - 192) * 256 + t;     // (row, h)
        int row = idx >> 3, h = idx & 7;
        int tt = token_type[row];
        short qe[32], ke[32];
        #pragma unroll
        for (int j = 0; j < 32; j++) {
            if (j < 8) {
                qe[j] = f2bf(typepair_bias[(tt * 8 + j) * 8 + h]);
                ke[j] = (j == tt) ? (short)0x3F80 : (short)0;   // bf16 1.0
            } else { qe[j] = 0; ke[j] = 0; }
        }
        size_t base = ((size_t)h * NTOK + row) * EXTD + 32;
        #pragma unroll
        for (int k = 0; k < 4; k++) {
            *(short8*)&qh[base + k * 8] = *(short8*)&qe[k * 8];
            *(short8*)&kh[base + k * 8] = *(short8*)&ke[k * 8];
        }
    } else {
        cnt2[(b - 256) * 256 + t] = 0;
        cnt2[(b - 256) * 256 + t + 8192] = 0;
        cnt2[(b - 256) * 256 + t + 16384] = 0;
        cnt2[(b - 256) * 256 + t + 24576] = 0;
    }
}

// ---------------- bf16 MFMA GEMM, 32x64 tile, BK=32, 256 thr -------------------
template<int EPI>
__global__ __launch_bounds__(256) void gemm32_kernel(
    const short* __restrict__ A, const short* __restrict__ Bt,
    const float* __restrict__ bias, const float* __restrict__ resid,
    void* __restrict__ out_, int M, int N, int K)
{
    __shared__ short A_lds[32 * 40];
    __shared__ short B_lds[64 * 40];

    const int t = threadIdx.x;
    const int w = t >> 6, lane = t & 63, c = lane & 15, g = lane >> 4;
    const int row0 = blockIdx.y * 32, col0 = blockIdx.x * 64;
    const int srow = t >> 2, sk = (t & 3) * 8;

    f32x4 acc[2] = {};

    for (int k0 = 0; k0 < K; k0 += 32) {
        if (t < 128)
            *(short8*)&A_lds[srow * 40 + sk] = *(const short8*)&A[(size_t)(row0 + srow) * K + k0 + sk];
        *(short8*)&B_lds[srow * 40 + sk] = *(const short8*)&Bt[(size_t)(col0 + srow) * K + k0 + sk];
        __syncthreads();
        short8 af = *(const short8*)&A_lds[((w & 1) * 16 + c) * 40 + g * 8];
        #pragma unroll
        for (int nf = 0; nf < 2; nf++) {
            short8 bf = *(const short8*)&B_lds[((w >> 1) * 32 + nf * 16 + c) * 40 + g * 8];
            acc[nf] = __builtin_amdgcn_mfma_f32_16x16x32_bf16(af, bf, acc[nf], 0, 0, 0);
        }
        __syncthreads();
    }

    #pragma unroll
    for (int nf = 0; nf < 2; nf++) {
        #pragma unroll
        for (int reg = 0; reg < 4; reg++) {
            int row = row0 + (w & 1) * 16 + g * 4 + reg;
            int col = col0 + (w >> 1) * 32 + nf * 16 + c;
            float v = acc[nf][reg] + bias[col];
            if (EPI == 2) {
                ((float*)out_)[(size_t)row * N + col] = v + resid[(size_t)row * N + col];
            } else {
                v = 0.5f * v * (1.0f + erff(v * 0.70710678118654752f));
                ((short*)out_)[(size_t)row * N + col] = f2bf(v);
            }
        }
    }
}

// Fused QKV GEMM (32x64): q -> qh[h][row][0..31] (scaled), k -> kh, v -> vt
__global__ __launch_bounds__(256) void gemm32_qkv_kernel(
    const short* __restrict__ A, const short* __restrict__ Bt,
    const float* __restrict__ bq, const float* __restrict__ bk, const float* __restrict__ bv,
    short* __restrict__ qh, short* __restrict__ kh, short* __restrict__ vt)
{
    const int K = CDIM;
    __shared__ short A_lds[32 * 40];
    __shared__ short B_lds[64 * 40];

    const int t = threadIdx.x;
    const int w = t >> 6, lane = t & 63, c = lane & 15, g = lane >> 4;
    const int row0 = blockIdx.y * 32, col0 = blockIdx.x * 64;
    const int srow = t >> 2, sk = (t & 3) * 8;

    f32x4 acc[2] = {};

    for (int k0 = 0; k0 < K; k0 += 32) {
        if (t < 128)
            *(short8*)&A_lds[srow * 40 + sk] = *(const short8*)&A[(size_t)(row0 + srow) * K + k0 + sk];
        *(short8*)&B_lds[srow * 40 + sk] = *(const short8*)&Bt[(size_t)(col0 + srow) * K + k0 + sk];
        __syncthreads();
        short8 af = *(const short8*)&A_lds[((w & 1) * 16 + c) * 40 + g * 8];
        #pragma unroll
        for (int nf = 0; nf < 2; nf++) {
            short8 bf = *(const short8*)&B_lds[((w >> 1) * 32 + nf * 16 + c) * 40 + g * 8];
            acc[nf] = __builtin_amdgcn_mfma_f32_16x16x32_bf16(af, bf, acc[nf], 0, 0, 0);
        }
        __syncthreads();
    }

    const int region = col0 >> 8;           // 0=q, 1=k, 2=v
    const int colr0 = col0 & 255;
    const float* bias = (region == 0) ? bq : (region == 1) ? bk : bv;
    #pragma unroll
    for (int nf = 0; nf < 2; nf++) {
        #pragma unroll
        for (int reg = 0; reg < 4; reg++) {
            int row = row0 + (w & 1) * 16 + g * 4 + reg;
            int col = colr0 + (w >> 1) * 32 + nf * 16 + c;
            float v = acc[nf][reg] + bias[col];
            if (region == 0) v *= 0.17677669529663687f;   // 1/sqrt(32)
            short bb = f2bf(v);
            size_t hidx = ((size_t)(col >> 5) * NTOK + row) * EXTD + (col & 31);
            if (region == 0)      qh[hidx] = bb;
            else if (region == 1) kh[hidx] = bb;
            else                  vt[(size_t)col * NTOK + row] = bb;   // V^T direct
        }
    }
}

// ---------------- Edge CSR build, bucketed by (src, dst>>7) --------------------
__global__ void edge_hist2_kernel(const int* __restrict__ src, const int* __restrict__ dst,
    int* __restrict__ cnt, int E)
{
    int e = blockIdx.x * blockDim.x + threadIdx.x;
    if (e < E) atomicAdd(&cnt[src[e] * NTILE + (dst[e] >> 7)], 1);
}

__global__ __launch_bounds__(256) void edge_scan2_kernel(const int* __restrict__ cnt,
    int* __restrict__ row_ptr, int* __restrict__ wcur)
{
    __shared__ int sums[256];
    int t = threadIdx.x;
    int base = t * 128;
    int s = 0;
    for (int i = 0; i < 128; i++) s += cnt[base + i];
    sums[t] = s;
    __syncthreads();
    for (int off = 1; off < 256; off <<= 1) {
        int v = (t >= off) ? sums[t - off] : 0;
        __syncthreads();
        sums[t] += v;
        __syncthreads();
    }
    int run = (t == 0) ? 0 : sums[t - 1];
    for (int i = 0; i < 128; i++) {
        row_ptr[base + i] = run;
        wcur[base + i] = run;
        run += cnt[base + i];
    }
    if (t == 255) row_ptr[NTOK * NTILE] = run;
}

__global__ void edge_scatter2_kernel(const int* __restrict__ src, const int* __restrict__ dst,
    const int* __restrict__ rel, int* __restrict__ wcur, int2* __restrict__ pairs, int E)
{
    int e = blockIdx.x * blockDim.x + threadIdx.x;
    if (e < E) {
        int d = dst[e];
        int pos = atomicAdd(&wcur[src[e] * NTILE + (d >> 7)], 1);
        pairs[pos] = make_int2(d, rel[e]);
    }
}

// ================= Materialized-S attention (big-ws path) ======================
// Phase A: S[h][n][m] = qh . kh (K=64 ext -> +typepair, q pre-scaled). 64x64 tile.
__global__ __launch_bounds__(256) void sgemm_kernel(
    const short* __restrict__ qh, const short* __restrict__ kh,
    short* __restrict__ S)
{
    __shared__ short A_lds[64 * LE];
    __shared__ short B_lds[64 * LE];
    const int t = threadIdx.x;
    const int w = t >> 6, lane = t & 63, c = lane & 15, g = lane >> 4;
    const int h = blockIdx.z;
    const int m0 = blockIdx.x * 64, n0 = blockIdx.y * 64;

    {
        int r = t >> 3, off = (t & 7) * 8;
        *(short8*)&A_lds[r * LE + off] =
            *(const short8*)&qh[((size_t)h * NTOK + n0 + r) * EXTD + off];
        *(short8*)&A_lds[(r + 32) * LE + off] =
            *(const short8*)&qh[((size_t)h * NTOK + n0 + 32 + r) * EXTD + off];
        *(short8*)&B_lds[r * LE + off] =
            *(const short8*)&kh[((size_t)h * NTOK + m0 + r) * EXTD + off];
        *(short8*)&B_lds[(r + 32) * LE + off] =
            *(const short8*)&kh[((size_t)h * NTOK + m0 + 32 + r) * EXTD + off];
    }
    __syncthreads();

    short8 alo = *(const short8*)&A_lds[(w * 16 + c) * LE + g * 8];
    short8 ahi = *(const short8*)&A_lds[(w * 16 + c) * LE + 32 + g * 8];
    f32x4 acc[4] = {};
    #pragma unroll
    for (int nf = 0; nf < 4; nf++) {
        short8 blo = *(const short8*)&B_lds[(nf * 16 + c) * LE + g * 8];
        short8 bhi = *(const short8*)&B_lds[(nf * 16 + c) * LE + 32 + g * 8];
        acc[nf] = __builtin_amdgcn_mfma_f32_16x16x32_bf16(alo, blo, acc[nf], 0, 0, 0);
        acc[nf] = __builtin_amdgcn_mfma_f32_16x16x32_bf16(ahi, bhi, acc[nf], 0, 0, 0);
    }

    #pragma unroll
    for (int nf = 0; nf < 4; nf++)
        #pragma unroll
        for (int reg = 0; reg < 4; reg++) {
            int row = n0 + w * 16 + g * 4 + reg;
            int col = m0 + nf * 16 + c;
            S[((size_t)h * NTOK + row) * NTOK + col] = f2bf(acc[nf][reg]);
        }
}

// Phase B: row softmax + temporal + edge bias. One wave per (h,n) row; in-place
// P (normalized) over S. Block = 4 waves = 4 rows.
__global__ __launch_bounds__(256) void softmax_kernel(
    short* __restrict__ S,
    const float* __restrict__ time_vec, const int* __restrict__ seed_ptr,
    const float* __restrict__ adj_rel_bias, const float* __restrict__ temp_bias,
    const int* __restrict__ row_ptr2, const int2* __restrict__ pairs2)
{
    __shared__ float rowbuf[4][NTOK];   // 32 KB

    int t = threadIdx.x, wv = t >> 6, lane = t & 63;
    int task = blockIdx.x * 4 + wv;
    int h = task >> 11, n = task & 2047;
    int seed = seed_ptr[0];
    bool temporal = (n < seed);
    float tn = time_vec[n];
    float* rb = rowbuf[wv];
    short* Srow = &S[((size_t)h * NTOK + n) * NTOK];

    // ---- stage row to LDS f32, temporal bias applied inline ----
    #pragma unroll
    for (int i = 0; i < 4; i++) {
        int m0 = i * 512 + lane * 8;
        short8 sv = *(const short8*)&Srow[m0];
        float v[8];
        #pragma unroll
        for (int j = 0; j < 8; j++) v[j] = bf2f(sv[j]);
        if (temporal) {
            float4 ta = *(const float4*)&time_vec[m0];
            float4 tb = *(const float4*)&time_vec[m0 + 4];
            float tv8[8] = { ta.x, ta.y, ta.z, ta.w, tb.x, tb.y, tb.z, tb.w };
            #pragma unroll
            for (int j = 0; j < 8; j++) {
                float dt = tv8[j] - tn;
                float ab = fabsf(dt) + 1e-6f;
                float sg = (dt > 0.0f) ? 1.0f : ((dt < 0.0f) ? -1.0f : 0.0f);
                float sl = sg * log1pf(ab);
                sl = fminf(fmaxf(sl, -5.0f), 5.0f);
                float norm = (sl + 5.0f) * (1.0f / (10.0f + 1e-9f));
                int bidx = (int)floorf(norm * 20.0f);
                bidx = min(max(bidx, 0), 20);
                v[j] += temp_bias[bidx * 8 + h];
            }
        }
        float4 lo = { v[0], v[1], v[2], v[3] };
        float4 hi = { v[4], v[5], v[6], v[7] };
        *(float4*)&rb[m0] = lo;
        *(float4*)&rb[m0 + 4] = hi;
    }
    __syncthreads();

    // ---- sparse edge scatter (whole-row CSR range, LDS float atomics) ----
    {
        int e0 = row_ptr2[n * NTILE], e1 = row_ptr2[(n + 1) * NTILE];
        for (int e = e0 + lane; e < e1; e += 64) {
            int2 pr = pairs2[e];
            atomicAdd(&rb[pr.x], adj_rel_bias[pr.y * 8 + h]);
        }
    }
    __syncthreads();

    // ---- exact softmax ----
    float vv[32];
    float mx = -INFINITY;
    #pragma unroll
    for (int i = 0; i < 4; i++) {
        float4 a = *(const float4*)&rb[i * 512 + lane * 8];
        float4 b = *(const float4*)&rb[i * 512 + lane * 8 + 4];
        vv[i * 8 + 0] = a.x; vv[i * 8 + 1] = a.y; vv[i * 8 + 2] = a.z; vv[i * 8 + 3] = a.w;
        vv[i * 8 + 4] = b.x; vv[i * 8 + 5] = b.y; vv[i * 8 + 6] = b.z; vv[i * 8 + 7] = b.w;
    }
    #pragma unroll
    for (int i = 0; i < 32; i++) mx = fmaxf(mx, vv[i]);
    #pragma unroll
    for (int off = 1; off < 64; off <<= 1) mx = fmaxf(mx, __shfl_xor(mx, off));
    float sum = 0.0f;
    #pragma unroll
    for (int i = 0; i < 32; i++) { vv[i] = __expf(vv[i] - mx); sum += vv[i]; }
    #pragma unroll
    for (int off = 1; off < 64; off <<= 1) sum += __shfl_xor(sum, off);
    float inv = 1.0f / sum;

    #pragma unroll
    for (int i = 0; i < 4; i++) {
        short p8[8];
        #pragma unroll
        for (int j = 0; j < 8; j++) p8[j] = f2bf(vv[i * 8 + j] * inv);
        *(short8*)&Srow[i * 512 + lane * 8] = *(short8*)p8;
    }
}

// Phase C: o[n][h*32+d] = P[h][n][:] . vt[h*32+d][:].  32 rows x 32 cols, BK=64.
__global__ __launch_bounds__(256) void pv_kernel(
    const short* __restrict__ P, const short* __restrict__ vt,
    short* __restrict__ o)
{
    __shared__ short A_lds[32 * LE];
    __shared__ short B_lds[32 * LE];
    const int t = threadIdx.x;
    const int w = t >> 6, lane = t & 63, c = lane & 15, g = lane >> 4;
    const int h = blockIdx.y;
    const int n0 = blockIdx.x * 32;
    const int rowblk = (w & 1) * 16, colblk = (w >> 1) * 16;

    f32x4 acc = {0.0f, 0.0f, 0.0f, 0.0f};

    for (int k0 = 0; k0 < NTOK; k0 += 64) {
        int r = t >> 3, off = (t & 7) * 8;
        *(short8*)&A_lds[r * LE + off] =
            *(const short8*)&P[((size_t)h * NTOK + n0 + r) * NTOK + k0 + off];
        *(short8*)&B_lds[r * LE + off] =
            *(const short8*)&vt[(size_t)(h * 32 + r) * NTOK + k0 + off];
        __syncthreads();
        short8 alo = *(const short8*)&A_lds[(rowblk + c) * LE + g * 8];
        short8 ahi = *(const short8*)&A_lds[(rowblk + c) * LE + 32 + g * 8];
        short8 blo = *(const short8*)&B_lds[(colblk + c) * LE + g * 8];
        short8 bhi = *(const short8*)&B_lds[(colblk + c) * LE + 32 + g * 8];
        acc = __builtin_amdgcn_mfma_f32_16x16x32_bf16(alo, blo, acc, 0, 0, 0);
        acc = __builtin_amdgcn_mfma_f32_16x16x32_bf16(ahi, bhi, acc, 0, 0, 0);
        __syncthreads();
    }

    #pragma unroll
    for (int reg = 0; reg < 4; reg++) {
        int row = n0 + rowblk + g * 4 + reg;
        int col = h * 32 + colblk + c;
        o[(size_t)row * CDIM + col] = f2bf(acc[reg]);
    }
}

// ================= Flash attention fallback (small-ws path) ====================
#define QBLK 32
#define KBLK 128

__global__ __launch_bounds__(256) void attn_mfma3_kernel(
    const short* __restrict__ qh, const short* __restrict__ kh,
    const short* __restrict__ vt,
    const float* __restrict__ time_vec, const int* __restrict__ seed_ptr,
    const float* __restrict__ adj_rel_bias, const float* __restrict__ temp_bias,
    const int* __restrict__ row_ptr2, const int2* __restrict__ pairs2,
    float* __restrict__ Op_part, float2* __restrict__ ml_part)
{
    __shared__ __align__(16) short Q_lds[QBLK * LE];
    __shared__ __align__(16) short K_lds[KBLK * LE];
    __shared__ __align__(16) short Vt_lds[DHEAD * 136];
    __shared__ __align__(16) unsigned int P32[QBLK * 68];
    __shared__ float tcol_s[KBLK];
    __shared__ float temp_h[21];
    __shared__ float adj_h[12];
    __shared__ float2 ml[2][QBLK];

    const int h  = blockIdx.y;
    const int n0 = blockIdx.x * QBLK;
    const int sblk = blockIdx.z;
    const int t  = threadIdx.x;
    const int wv = t >> 6, lane = t & 63, c = lane & 15, g = lane >> 4;
    const int rowblk  = (wv & 1) * 16;
    const int halfIdx = wv >> 1;
    const int colhalf = halfIdx * 64;
    const int seed = seed_ptr[0];
    const bool blockTemporal = (n0 < seed);
    const int gt0 = sblk * TPS;

    {
        int row = t >> 3, off = (t & 7) * 8;
        *(short8*)&Q_lds[row * LE + off] =
            *(const short8*)&qh[((size_t)h * NTOK + n0 + row) * EXTD + off];
    }
    if (t < 21)  temp_h[t] = temp_bias[t * HHEADS + h];
    if (t < 12)  adj_h[t] = adj_rel_bias[t * HHEADS + h];

    const int nrow = n0 + rowblk + c;
    const bool rowTemporal = (nrow < seed);
    const float tn = time_vec[nrow];

    int2 rp01 = *(const int2*)&row_ptr2[nrow * NTILE + gt0];
    int  rp2  = row_ptr2[nrow * NTILE + gt0 + 2];

    const int krow = t >> 3, koff = (t & 7) * 8;
    const int vrow = t >> 4, voff = (t & 15) * 8;
    short8 kr0, kr1, kr2, kr3, vr0, vr1;
    float tcr = 0.0f;

    auto LOADT = [&](int gt) {
        int m0 = gt * KBLK;
        const short* kp = &kh[((size_t)h * NTOK + m0 + krow) * EXTD + koff];
        kr0 = *(const short8*)kp;
        kr1 = *(const short8*)(kp + (size_t)32 * EXTD);
        kr2 = *(const short8*)(kp + (size_t)64 * EXTD);
        kr3 = *(const short8*)(kp + (size_t)96 * EXTD);
        const short* vp = &vt[(size_t)(h * 32 + vrow) * NTOK + m0 + voff];
        vr0 = *(const short8*)vp;
        vr1 = *(const short8*)(vp + (size_t)16 * NTOK);
        if (blockTemporal && t < 128) tcr = time_vec[m0 + t];
    };
    auto WRITET = [&]() {
        *(short8*)&K_lds[krow * LE + koff]        = kr0;
        *(short8*)&K_lds[(krow + 32) * LE + koff] = kr1;
        *(short8*)&K_lds[(krow + 64) * LE + koff] = kr2;
        *(short8*)&K_lds[(krow + 96) * LE + koff] = kr3;
        *(short8*)&Vt_lds[vrow * 136 + voff]        = vr0;
        *(short8*)&Vt_lds[(vrow + 16) * 136 + voff] = vr1;
        if (blockTemporal && t < 128) tcol_s[t] = tcr;
    };

    float m_run = -INFINITY, l_run = 0.0f;
    f32x4 oacc[2] = {{0,0,0,0},{0,0,0,0}};
    const f32x4 zf = {0.0f, 0.0f, 0.0f, 0.0f};

    LOADT(gt0);
    WRITET();

    for (int tile = 0; tile < TPS; ++tile) {
        __syncthreads();
        if (tile + 1 < TPS) LOADT(gt0 + tile + 1);

        short8 qlo = *(const short8*)&Q_lds[(rowblk + c) * LE + g * 8];
        short8 qhi = *(const short8*)&Q_lds[(rowblk + c) * LE + 32 + g * 8];
        float vals[16];
        #pragma unroll
        for (int blk = 0; blk < 4; blk++) {
            const short* kb = &K_lds[(colhalf + blk * 16 + c) * LE];
            short8 klo = *(const short8*)(kb + g * 8);
            short8 khi = *(const short8*)(kb + 32 + g * 8);
            f32x4 acc = __builtin_amdgcn_mfma_f32_16x16x32_bf16(klo, qlo, zf, 0, 0, 0);
            acc = __builtin_amdgcn_mfma_f32_16x16x32_bf16(khi, qhi, acc, 0, 0, 0);
            #pragma unroll
            for (int reg = 0; reg < 4; reg++) vals[blk * 4 + reg] = acc[reg];
        }

        if (rowTemporal) {
            #pragma unroll
            for (int blk = 0; blk < 4; blk++) {
                #pragma unroll
                for (int reg = 0; reg < 4; reg++) {
                    float dt = tcol_s[colhalf + blk * 16 + g * 4 + reg] - tn;
                    float ab = fabsf(dt) + 1e-6f;
                    float sg = (dt > 0.0f) ? 1.0f : ((dt < 0.0f) ? -1.0f : 0.0f);
                    float sl = sg * log1pf(ab);
                    sl = fminf(fmaxf(sl, -5.0f), 5.0f);
                    float norm = (sl + 5.0f) * (1.0f / (10.0f + 1e-9f));
                    int bidx = (int)floorf(norm * 20.0f);
                    bidx = min(max(bidx, 0), 20);
                    vals[blk * 4 + reg] += temp_h[bidx];
                }
            }
        }
        {
            int e0 = (tile == 0) ? rp01.x : rp01.y;
            int e1 = (tile == 0) ? rp01.y : rp2;
            for (int e = e0; e < e1; ++e) {
                int2 pr = pairs2[e];
                int dloc = pr.x & 127;
                if ((dloc >> 6) == halfIdx) {
                    int ml64 = dloc & 63;
                    if (((ml64 >> 2) & 3) == g) {
                        float ab = adj_h[pr.y];
                        int li = (ml64 >> 4) * 4 + (ml64 & 3);
                        #pragma unroll
                        for (int i = 0; i < 16; i++) vals[i] += (i == li) ? ab : 0.0f;
                    }
                }
            }
        }

        float tmax = vals[0];
        #pragma unroll
        for (int i = 1; i < 16; i++) tmax = fmaxf(tmax, vals[i]);
        tmax = fmaxf(tmax, __shfl_xor(tmax, 16));
        tmax = fmaxf(tmax, __shfl_xor(tmax, 32));
        float m_new = fmaxf(m_run, tmax);
        float psum = 0.0f;
        #pragma unroll
        for (int i = 0; i < 16; i++) { vals[i] = __expf(vals[i] - m_new); psum += vals[i]; }
        psum += __shfl_xor(psum, 16);
        psum += __shfl_xor(psum, 32);
        float scale = __expf(m_run - m_new);
        m_run = m_new;
        l_run = l_run * scale + psum;

        #pragma unroll
        for (int blk = 0; blk < 4; blk++) {
            #pragma unroll
            for (int r = 0; r < 2; r++) {
                unsigned lo = (unsigned short)f2bf(vals[blk * 4 + 2 * r]);
                unsigned hi = (unsigned short)f2bf(vals[blk * 4 + 2 * r + 1]);
                P32[(rowblk + c) * 68 + halfIdx * 32 + blk * 8 + g * 2 + r] = lo | (hi << 16);
            }
        }

        float scr[4];
        #pragma unroll
        for (int reg = 0; reg < 4; reg++) scr[reg] = __shfl(scale, 4 * g + reg);
        #pragma unroll
        for (int dblk = 0; dblk < 2; dblk++)
            #pragma unroll
            for (int reg = 0; reg < 4; reg++) oacc[dblk][reg] *= scr[reg];
        #pragma unroll
        for (int kc = 0; kc < 2; kc++) {
            short8 pa = *(const short8*)&P32[(rowblk + c) * 68 + halfIdx * 32 + kc * 16 + g * 4];
            #pragma unroll
            for (int dblk = 0; dblk < 2; dblk++) {
                short8 vb = *(const short8*)&Vt_lds[(dblk * 16 + c) * 136 + colhalf + kc * 32 + g * 8];
                oacc[dblk] = __builtin_amdgcn_mfma_f32_16x16x32_bf16(pa, vb, oacc[dblk], 0, 0, 0);
            }
        }

        __syncthreads();
        if (tile + 1 < TPS) WRITET();
    }

    __syncthreads();
    if (lane < 16) ml[halfIdx][rowblk + lane] = make_float2(m_run, l_run);
    __syncthreads();

    float* Op = (float*)K_lds;
    #pragma unroll
    for (int reg = 0; reg < 4; reg++) {
        int rw = rowblk + 4 * g + reg;
        float2 a0 = ml[0][rw], a1 = ml[1][rw];
        float mm = fmaxf(a0.x, a1.x);
        float wh = __expf((halfIdx == 0 ? a0.x : a1.x) - mm);
        Op[halfIdx * 32 * 36 + rw * 36 + c]      = oacc[0][reg] * wh;
        Op[halfIdx * 32 * 36 + rw * 36 + 16 + c] = oacc[1][reg] * wh;
    }
    __syncthreads();

    {
        int row = t >> 3, d0 = (t & 7) * 4;
        float2 a0 = ml[0][row], a1 = ml[1][row];
        float mm = fmaxf(a0.x, a1.x);
        float w0 = __expf(a0.x - mm), w1 = __expf(a1.x - mm);
        float lc = a0.y * w0 + a1.y * w1;
        float4 pa = *(const float4*)&Op[row * 36 + d0];
        float4 pb = *(const float4*)&Op[(32 + row) * 36 + d0];
        float4 sum;
        sum.x = pa.x + pb.x; sum.y = pa.y + pb.y;
        sum.z = pa.z + pb.z; sum.w = pa.w + pb.w;
        *(float4*)&Op_part[((size_t)sblk * NTOK + n0 + row) * CDIM + h * DHEAD + d0] = sum;
        if ((t & 7) == 0)
            ml_part[((size_t)sblk * NTOK + n0 + row) * HHEADS + h] = make_float2(mm, lc);
    }
}

__global__ __launch_bounds__(256) void attn_reduce_kernel(
    const float* __restrict__ Op_part, const float2* __restrict__ ml_part,
    short* __restrict__ o)
{
    int row = blockIdx.x;
    int t = threadIdx.x;
    int h = t >> 5, d = t & 31;

    float2 a[SPLITS];
    float mm = -INFINITY;
    #pragma unroll
    for (int s = 0; s < SPLITS; s++) {
        a[s] = ml_part[((size_t)s * NTOK + row) * HHEADS + h];
        mm = fmaxf(mm, a[s].x);
    }
    float l = 0.0f, w[SPLITS];
    #pragma unroll
    for (int s = 0; s < SPLITS; s++) { w[s] = __expf(a[s].x - mm); l += a[s].y * w[s]; }
    float inv = 1.0f / l;
    size_t idx = (size_t)row * CDIM + h * DHEAD + d;
    float acc = 0.0f;
    #pragma unroll
    for (int s = 0; s < SPLITS; s++)
        acc += w[s] * Op_part[(size_t)s * NTOK * CDIM + idx];
    o[idx] = f2bf(acc * inv);
}

// ---------------- launch --------------------------------------------------------
extern "C" void kernel_launch(void* const* d_in, const int* in_sizes, int n_in,
                              void* d_out, int out_size, void* d_ws, size_t ws_size,
                              hipStream_t stream)
{
    (void)in_sizes; (void)n_in; (void)out_size;
    const float* X        = (const float*)d_in[0];
    const int* token_type = (const int*)d_in[1];
    const int* edge_src   = (const int*)d_in[2];
    const int* edge_dst   = (const int*)d_in[3];
    const int* edge_rel   = (const int*)d_in[4];
    const float* time_vec = (const float*)d_in[5];
    const int* seed_ptr   = (const int*)d_in[6];
    const float* Wq = (const float*)d_in[7];  const float* bq = (const float*)d_in[8];
    const float* Wk = (const float*)d_in[9];  const float* bk = (const float*)d_in[10];
    const float* Wv = (const float*)d_in[11]; const float* bv = (const float*)d_in[12];
    const float* Wo = (const float*)d_in[13]; const float* bo = (const float*)d_in[14];
    const float* ln1_g = (const float*)d_in[15]; const float* ln1_b = (const float*)d_in[16];
    const float* ln2_g = (const float*)d_in[17]; const float* ln2_b = (const float*)d_in[18];
    const float* W1 = (const float*)d_in[19]; const float* b1 = (const float*)d_in[20];
    const float* W2 = (const float*)d_in[21]; const float* b2 = (const float*)d_in[22];
    const float* adj_rel_bias  = (const float*)d_in[23];
    const float* typepair_bias = (const float*)d_in[24];
    const float* temp_bias     = (const float*)d_in[25];
    float* out = (float*)d_out;

    char* base = (char*)d_ws;
    size_t off = 0;
    auto alloc = [&](size_t bytes) { char* p = base + off; off += (bytes + 255) & ~(size_t)255; return p; };
    short* qh_bf   = (short*)alloc((size_t)HHEADS * NTOK * EXTD * 2);
    short* kh_bf   = (short*)alloc((size_t)HHEADS * NTOK * EXTD * 2);
    short* vt_bf   = (short*)alloc((size_t)256 * NTOK * 2);
    short* h1_bf   = (short*)alloc((size_t)NTOK * 256 * 2);
    short* h2_bf   = (short*)alloc((size_t)NTOK * 256 * 2);
    short* o_bf    = (short*)alloc((size_t)NTOK * 256 * 2);
    short* mid_bf  = (short*)alloc((size_t)NTOK * 1024 * 2);
    float* xb      = (float*)alloc((size_t)NTOK * 256 * 4);
    short* wt_qkv  = (short*)alloc((size_t)768 * 256 * 2);
    short* wot     = (short*)alloc((size_t)256 * 256 * 2);
    short* w1t     = (short*)alloc((size_t)1024 * 256 * 2);
    short* w2t     = (short*)alloc((size_t)256 * 1024 * 2);
    int2*  pairs2  = (int2*)alloc((size_t)NEDGE * 8);
    int*   cnt2    = (int*)alloc((size_t)NTOK * NTILE * 4);
    int*   rowptr2 = (int*)alloc(((size_t)NTOK * NTILE + 1) * 4);
    int*   wcur2   = (int*)alloc((size_t)NTOK * NTILE * 4);

    const size_t s_bytes = (size_t)HHEADS * NTOK * NTOK * 2;   // 64 MB
    const bool bigws = (ws_size >= off + s_bytes + (1u << 20));

    // common prologue
    prep_kernel<<<288, 256, 0, stream>>>(Wq, Wk, Wv, Wo, W1, W2,
                                         wt_qkv, wot, w1t, w2t,
                                         token_type, typepair_bias,
                                         qh_bf, kh_bf, cnt2);
    edge_hist2_kernel<<<NEDGE / 256, 256, 0, stream>>>(edge_src, edge_dst, cnt2, NEDGE);
    edge_scan2_kernel<<<1, 256, 0, stream>>>(cnt2, rowptr2, wcur2);
    edge_scatter2_kernel<<<NEDGE / 256, 256, 0, stream>>>(edge_src, edge_dst, edge_rel, wcur2, pairs2, NEDGE);

    ln4_kernel<<<NTOK / 4, 256, 0, stream>>>(X, ln1_g, ln1_b, h1_bf);
    gemm32_qkv_kernel<<<dim3(12, 64), 256, 0, stream>>>(h1_bf, wt_qkv, bq, bk, bv,
                                                        qh_bf, kh_bf, vt_bf);

    if (bigws) {
        short* S = (short*)alloc(s_bytes);
        sgemm_kernel<<<dim3(32, 32, 8), 256, 0, stream>>>(qh_bf, kh_bf, S);
        softmax_kernel<<<NTOK * HHEADS / 4, 256, 0, stream>>>(
            S, time_vec, seed_ptr, adj_rel_bias, temp_bias, rowptr2, pairs2);
        pv_kernel<<<dim3(64, 8), 256, 0, stream>>>(S, vt_bf, o_bf);
    } else {
        float* Op_part  = (float*)alloc((size_t)SPLITS * NTOK * CDIM * 4);
        float2* ml_part = (float2*)alloc((size_t)SPLITS * NTOK * HHEADS * 8);
        attn_mfma3_kernel<<<dim3(NTOK / QBLK, HHEADS, SPLITS), 256, 0, stream>>>(
            qh_bf, kh_bf, vt_bf, time_vec, seed_ptr,
            adj_rel_bias, temp_bias, rowptr2, pairs2, Op_part, ml_part);
        attn_reduce_kernel<<<NTOK, 256, 0, stream>>>(Op_part, ml_part, o_bf);
    }

    // x = X + o @ Wo + bo   (f32 out)
    gemm32_kernel<2><<<dim3(4, 64), 256, 0, stream>>>(o_bf, wot, bo, X, xb, NTOK, 256, 256);

    // LN2 -> bf16
    ln4_kernel<<<NTOK / 4, 256, 0, stream>>>(xb, ln2_g, ln2_b, h2_bf);

    // FFN
    gemm32_kernel<3><<<dim3(16, 64), 256, 0, stream>>>(h2_bf, w1t, b1, nullptr, mid_bf, NTOK, 1024, 256);
    gemm32_kernel<2><<<dim3(4, 64), 256, 0, stream>>>(mid_bf, w2t, b2, xb, out, NTOK, 256, 1024);
}